// Round 2
// baseline (5746.402 us; speedup 1.0000x reference)
//
#include <hip/hip_runtime.h>
#include <hip/hip_bf16.h>

typedef __hip_bfloat16 bf16;

__device__ __forceinline__ float gelu_f(float v) {
    return 0.5f * v * (1.f + erff(v * 0.70710678118654752440f));
}

// ---------------------------------------------------------------------------
__global__ __launch_bounds__(256) void zero_k(float* __restrict__ p, int n) {
    int i = blockIdx.x * 256 + threadIdx.x;
    if (i < n) p[i] = 0.f;
}

// ---------------------------------------------------------------------------
// Per-node GN stats of conv0 output (computed on the fly, h0 never stored).
// conv0: in_ch=1, w=3, stride=3, pad 1: h0[n][co][t] = sum_k W0[co,k]*x[3t-1+k] + b0[co]
// One block per node n; thread tid owns channel co=tid, loops t.
// ---------------------------------------------------------------------------
__global__ __launch_bounds__(256) void conv0_stats_k(
    const float* __restrict__ x, const float* __restrict__ W0,
    const float* __restrict__ b0, float* __restrict__ mu0, float* __restrict__ rstd0)
{
    __shared__ float xsl[3008];   // xsl[k] = x[k-1], xsl[0]=0 (left pad)
    __shared__ float ws[768];
    __shared__ float bs[256];
    __shared__ float red[512];
    const int n = blockIdx.x, tid = threadIdx.x;
    for (int i = tid; i < 3000; i += 256) xsl[i + 1] = x[(size_t)n * 3000 + i];
    if (tid == 0) xsl[0] = 0.f;
    for (int i = tid; i < 768; i += 256) ws[i] = W0[i];
    bs[tid] = b0[tid];
    __syncthreads();
    const float w0 = ws[tid * 3], w1 = ws[tid * 3 + 1], w2 = ws[tid * 3 + 2], bb = bs[tid];
    float s = 0.f, q = 0.f;
    for (int t = 0; t < 1000; t++) {
        // x[3t-1],x[3t],x[3t+1] -> xsl[3t],xsl[3t+1],xsl[3t+2]; broadcast LDS reads
        float v = w0 * xsl[3 * t] + w1 * xsl[3 * t + 1] + w2 * xsl[3 * t + 2] + bb;
        s += v; q += v * v;
    }
    red[tid] = s; red[256 + tid] = q;
    __syncthreads();
    for (int st = 128; st > 0; st >>= 1) {
        if (tid < st) { red[tid] += red[tid + st]; red[256 + tid] += red[256 + tid + st]; }
        __syncthreads();
    }
    if (tid == 0) {
        float m = red[0] * (1.f / 256000.f);
        float var = red[256] * (1.f / 256000.f) - m * m;
        mu0[n] = m;
        rstd0[n] = rsqrtf(var + 1e-5f);
    }
}

// ---------------------------------------------------------------------------
// Layer 1 fused: recompute conv0 -> GN0 -> GELU on the fly in LDS staging,
// then conv1 (CI=256,CO=256,w=2,s=2,pad1) as register-tiled LDS GEMM.
// Block: [64 co][32 t] for local node z (global n = n0+z). Raw conv1 out (bf16)
// + fused GN1 stat atomics.
// ---------------------------------------------------------------------------
__global__ __launch_bounds__(256) void conv1_fused_k(
    const float* __restrict__ x, const float* __restrict__ W0,
    const float* __restrict__ b0, const float* __restrict__ g0,
    const float* __restrict__ be0, const float* __restrict__ mu0,
    const float* __restrict__ rstd0, const float* __restrict__ W1,
    const float* __restrict__ b1, bf16* __restrict__ hout,
    float* __restrict__ ssum, float* __restrict__ ssq, int n0)
{
    __shared__ float lds_w[128][68];  // [ci_local*2+k][co_local]
    __shared__ float lds_x[64][68];   // [ci_local][pp]
    __shared__ float xs[192];
    __shared__ float w0s[768];
    __shared__ float aco[256], cco[256];
    __shared__ float red[512];
    const int z   = blockIdx.z;
    const int n   = n0 + z;
    const int co0 = blockIdx.x * 64;
    const int t0  = blockIdx.y * 32;
    const int tid = threadIdx.x;
    // x segment covering tin in [2t0-1, 2t0+62]: x idx in [6t0-4, 6t0+187]
    for (int i = tid; i < 192; i += 256) {
        int xg = 6 * t0 - 4 + i;
        xs[i] = (xg >= 0 && xg < 3000) ? x[(size_t)n * 3000 + xg] : 0.f;
    }
    for (int i = tid; i < 768; i += 256) w0s[i] = W0[i];
    {
        float rs = rstd0[n], m = mu0[n];
        float a = rs * g0[tid];
        aco[tid] = a;
        cco[tid] = (b0[tid] - m) * a + be0[tid];
    }
    __syncthreads();
    const int coi = tid & 15;
    const int tt  = tid >> 4;
    float acc[4][2] = {{0.f,0.f},{0.f,0.f},{0.f,0.f},{0.f,0.f}};
    const float* Wb = W1 + (size_t)co0 * 512;
    for (int ci0 = 0; ci0 < 256; ci0 += 64) {
        for (int idx = tid; idx < 64 * 128; idx += 256) {
            int co = idx >> 7, q = idx & 127;
            lds_w[q][co] = Wb[(size_t)co * 512 + ci0 * 2 + q];
        }
        for (int idx = tid; idx < 64 * 64; idx += 256) {
            int ci_l = idx >> 6, pp = idx & 63;
            int ci = ci0 + ci_l;
            int tin = 2 * t0 - 1 + pp;
            float v = 0.f;
            if (tin >= 0 && tin < 1000) {
                // x[3*tin-1] == xs[3*pp] by construction
                float h = w0s[3 * ci] * xs[3 * pp] + w0s[3 * ci + 1] * xs[3 * pp + 1]
                        + w0s[3 * ci + 2] * xs[3 * pp + 2];
                v = gelu_f(h * aco[ci] + cco[ci]);
            }
            lds_x[ci_l][pp] = v;
        }
        __syncthreads();
        #pragma unroll 8
        for (int ci = 0; ci < 64; ci++) {
            const float4 xv = *(const float4*)&lds_x[ci][tt * 4];
            const float4 w0 = *(const float4*)&lds_w[2 * ci][coi * 4];
            const float4 w1 = *(const float4*)&lds_w[2 * ci + 1][coi * 4];
            acc[0][0] += w0.x * xv.x; acc[0][0] += w1.x * xv.y;
            acc[0][1] += w0.x * xv.z; acc[0][1] += w1.x * xv.w;
            acc[1][0] += w0.y * xv.x; acc[1][0] += w1.y * xv.y;
            acc[1][1] += w0.y * xv.z; acc[1][1] += w1.y * xv.w;
            acc[2][0] += w0.z * xv.x; acc[2][0] += w1.z * xv.y;
            acc[2][1] += w0.z * xv.z; acc[2][1] += w1.z * xv.w;
            acc[3][0] += w0.w * xv.x; acc[3][0] += w1.w * xv.y;
            acc[3][1] += w0.w * xv.z; acc[3][1] += w1.w * xv.w;
        }
        __syncthreads();
    }
    float lsum = 0.f, lsq = 0.f;
    #pragma unroll
    for (int c = 0; c < 4; c++) {
        const int co = co0 + coi * 4 + c;
        const float bv = b1[co];
        #pragma unroll
        for (int j = 0; j < 2; j++) {
            const int t = t0 + tt * 2 + j;
            if (t < 501) {
                float v = acc[c][j] + bv;
                hout[(size_t)z * 128256 + (size_t)co * 501 + t] = __float2bfloat16(v);
                lsum += v; lsq += v * v;
            }
        }
    }
    red[tid] = lsum; red[256 + tid] = lsq;
    __syncthreads();
    for (int st = 128; st > 0; st >>= 1) {
        if (tid < st) { red[tid] += red[tid + st]; red[256 + tid] += red[256 + tid + st]; }
        __syncthreads();
    }
    if (tid == 0) { atomicAdd(&ssum[n], red[0]); atomicAdd(&ssq[n], red[256]); }
}

// ---------------------------------------------------------------------------
// Layers 2..5: conv1d CI=256, w=2, stride=2, pad 1, bf16 in/out.
// hin/hout/ssum/ssq may be pre-offset for node chunking (blockIdx.z is local).
// ---------------------------------------------------------------------------
__global__ __launch_bounds__(256) void conv_s2_k(
    const bf16* __restrict__ hin, const float* __restrict__ W,
    const float* __restrict__ bias, bf16* __restrict__ hout,
    float* __restrict__ ssum, float* __restrict__ ssq,
    int CO, int T_in, int T_out)
{
    __shared__ float lds_w[128][68];
    __shared__ float lds_x[64][68];
    __shared__ float red[512];
    const int n   = blockIdx.z;
    const int co0 = blockIdx.x * 64;
    const int t0  = blockIdx.y * 32;
    const int tid = threadIdx.x;
    const int coi = tid & 15;
    const int tt  = tid >> 4;
    float acc[4][2] = {{0.f,0.f},{0.f,0.f},{0.f,0.f},{0.f,0.f}};
    const float* Wb = W + (size_t)co0 * 512;
    const bf16*  xb = hin + (size_t)n * 256 * T_in;
    for (int ci0 = 0; ci0 < 256; ci0 += 64) {
        for (int idx = tid; idx < 64 * 128; idx += 256) {
            int co = idx >> 7, q = idx & 127;
            lds_w[q][co] = Wb[(size_t)co * 512 + ci0 * 2 + q];
        }
        for (int idx = tid; idx < 64 * 64; idx += 256) {
            int ci = idx >> 6, pp = idx & 63;
            int tin = 2 * t0 - 1 + pp;
            float v = 0.f;
            if (tin >= 0 && tin < T_in) v = __bfloat162float(xb[(size_t)(ci0 + ci) * T_in + tin]);
            lds_x[ci][pp] = v;
        }
        __syncthreads();
        #pragma unroll 8
        for (int ci = 0; ci < 64; ci++) {
            const float4 xv = *(const float4*)&lds_x[ci][tt * 4];
            const float4 w0 = *(const float4*)&lds_w[2 * ci][coi * 4];
            const float4 w1 = *(const float4*)&lds_w[2 * ci + 1][coi * 4];
            acc[0][0] += w0.x * xv.x; acc[0][0] += w1.x * xv.y;
            acc[0][1] += w0.x * xv.z; acc[0][1] += w1.x * xv.w;
            acc[1][0] += w0.y * xv.x; acc[1][0] += w1.y * xv.y;
            acc[1][1] += w0.y * xv.z; acc[1][1] += w1.y * xv.w;
            acc[2][0] += w0.z * xv.x; acc[2][0] += w1.z * xv.y;
            acc[2][1] += w0.z * xv.z; acc[2][1] += w1.z * xv.w;
            acc[3][0] += w0.w * xv.x; acc[3][0] += w1.w * xv.y;
            acc[3][1] += w0.w * xv.z; acc[3][1] += w1.w * xv.w;
        }
        __syncthreads();
    }
    float lsum = 0.f, lsq = 0.f;
    #pragma unroll
    for (int c = 0; c < 4; c++) {
        const int co = co0 + coi * 4 + c;
        const float bv = bias[co];
        #pragma unroll
        for (int j = 0; j < 2; j++) {
            const int t = t0 + tt * 2 + j;
            if (t < T_out) {
                float v = acc[c][j] + bv;
                hout[(size_t)n * CO * T_out + (size_t)co * T_out + t] = __float2bfloat16(v);
                lsum += v; lsq += v * v;
            }
        }
    }
    red[tid] = lsum; red[256 + tid] = lsq;
    __syncthreads();
    for (int st = 128; st > 0; st >>= 1) {
        if (tid < st) { red[tid] += red[tid + st]; red[256 + tid] += red[256 + tid + st]; }
        __syncthreads();
    }
    if (tid == 0) { atomicAdd(&ssum[n], red[0]); atomicAdd(&ssq[n], red[256]); }
}

// ---------------------------------------------------------------------------
__global__ void gn_stats_k(const float* __restrict__ ssum, const float* __restrict__ ssq,
                           float* __restrict__ mu, float* __restrict__ rstd,
                           float invCT, int count)
{
    int i = blockIdx.x * blockDim.x + threadIdx.x;
    if (i < count) {
        float m = ssum[i] * invCT;
        float v = ssq[i] * invCT - m * m;
        mu[i] = m;
        rstd[i] = rsqrtf(v + 1e-5f);
    }
}

__global__ __launch_bounds__(256) void gn_gelu_k(
    bf16* __restrict__ h, const float* __restrict__ mu, const float* __restrict__ rstd,
    const float* __restrict__ g, const float* __restrict__ be, int C, int T, unsigned total)
{
    unsigned idx = blockIdx.x * 256u + threadIdx.x;
    if (idx >= total) return;
    unsigned ct = (unsigned)C * (unsigned)T;
    unsigned n = idx / ct;
    unsigned c = (idx - n * ct) / (unsigned)T;
    float v = __bfloat162float(h[idx]);
    v = (v - mu[n]) * rstd[n] * g[c] + be[c];
    h[idx] = __float2bfloat16(gelu_f(v));
}

// ---------------------------------------------------------------------------
// Readout 1x1: lat[n][t][d] = sum_c h5[n][c][t] * ro_w[c][d] + ro_b[d]
// ---------------------------------------------------------------------------
__global__ __launch_bounds__(256) void readout_k(
    const bf16* __restrict__ h5, const float* __restrict__ row,
    const float* __restrict__ rob, float* __restrict__ lat)
{
    __shared__ float lh[2112];
    __shared__ float lw[4096];
    __shared__ float lb[64];
    const int n = blockIdx.x, tid = threadIdx.x;
    for (int idx = tid; idx < 2112; idx += 256) lh[idx] = __bfloat162float(h5[(size_t)n * 2112 + idx]);
    for (int idx = tid; idx < 4096; idx += 256) lw[idx] = row[idx];
    if (tid < 64) lb[tid] = rob[tid];
    __syncthreads();
    for (int idx = tid; idx < 2112; idx += 256) {
        int t = idx >> 6, d = idx & 63;
        float a = lb[d];
        #pragma unroll 8
        for (int c = 0; c < 64; c++) a += lh[c * 33 + t] * lw[c * 64 + d];
        lat[(size_t)n * 2112 + idx] = a;   // [t][d]
    }
}

// ---------------------------------------------------------------------------
// Message round part 1: A = lat @ W_top ; Bv = lat @ W_bot + b  (per node)
// ---------------------------------------------------------------------------
__global__ __launch_bounds__(256) void msg_pre_k(
    const float* __restrict__ lat, const float* __restrict__ W,
    const float* __restrict__ b, float* __restrict__ A, float* __restrict__ Bv)
{
    __shared__ float ll[2112];
    __shared__ float lw[8192];
    __shared__ float lb[64];
    const int n = blockIdx.x, tid = threadIdx.x;
    for (int idx = tid; idx < 2112; idx += 256) ll[idx] = lat[(size_t)n * 2112 + idx];
    for (int idx = tid; idx < 8192; idx += 256) lw[idx] = W[idx];
    if (tid < 64) lb[tid] = b[tid];
    __syncthreads();
    for (int idx = tid; idx < 2112; idx += 256) {
        int t = idx >> 6, d = idx & 63;
        float a = 0.f, bb = lb[d];
        #pragma unroll 8
        for (int k = 0; k < 64; k++) {
            float xv = ll[t * 64 + k];
            a  += xv * lw[k * 64 + d];
            bb += xv * lw[(64 + k) * 64 + d];
        }
        A[(size_t)n * 2112 + idx]  = a;
        Bv[(size_t)n * 2112 + idx] = bb;
    }
}

// Part 2: latout[j] = latin[j] + (1/8) * sum_{i != j in sample} relu(A[i] + Bv[j])
__global__ __launch_bounds__(256) void msg_comb_k(
    const float* __restrict__ latin, const float* __restrict__ A,
    const float* __restrict__ Bv, float* __restrict__ latout)
{
    const int n = blockIdx.x, tid = threadIdx.x;
    const int b9 = (n / 9) * 9, j = n - b9;
    for (int idx = tid; idx < 2112; idx += 256) {
        float base = Bv[(size_t)n * 2112 + idx];
        float s = 0.f;
        #pragma unroll
        for (int i = 0; i < 9; i++) {
            if (i == j) continue;
            float v = A[(size_t)(b9 + i) * 2112 + idx] + base;
            s += fmaxf(v, 0.f);
        }
        latout[(size_t)n * 2112 + idx] = latin[(size_t)n * 2112 + idx] + s * 0.125f;
    }
}

// ---------------------------------------------------------------------------
// Final: y=sum_views lat; z=relu(y@W1+b1); u=(z@W2+b2)/9; out[b][e][t]=u@pw+pb
// ---------------------------------------------------------------------------
__global__ __launch_bounds__(256) void final_k(
    const float* __restrict__ lat,
    const float* __restrict__ w1, const float* __restrict__ b1,
    const float* __restrict__ w2, const float* __restrict__ b2,
    const float* __restrict__ pw, const float* __restrict__ pb,
    float* __restrict__ out)
{
    __shared__ float ly[2112], lz[2112];
    __shared__ float lw1[4096], lw2[4096], lpw[2048];
    __shared__ float lb1[64], lb2[64], lpb[32];
    const int b = blockIdx.x, tid = threadIdx.x;
    for (int idx = tid; idx < 4096; idx += 256) { lw1[idx] = w1[idx]; lw2[idx] = w2[idx]; }
    for (int idx = tid; idx < 2048; idx += 256) lpw[idx] = pw[idx];
    if (tid < 64) { lb1[tid] = b1[tid]; lb2[tid] = b2[tid]; }
    if (tid < 32) lpb[tid] = pb[tid];
    for (int idx = tid; idx < 2112; idx += 256) {
        float s = 0.f;
        #pragma unroll
        for (int jj = 0; jj < 9; jj++) s += lat[((size_t)b * 9 + jj) * 2112 + idx];
        ly[idx] = s;
    }
    __syncthreads();
    for (int idx = tid; idx < 2112; idx += 256) {
        int t = idx >> 6, d = idx & 63;
        float s = lb1[d];
        #pragma unroll 8
        for (int k = 0; k < 64; k++) s += ly[t * 64 + k] * lw1[k * 64 + d];
        lz[idx] = fmaxf(s, 0.f);
    }
    __syncthreads();
    for (int idx = tid; idx < 2112; idx += 256) {
        int t = idx >> 6, d = idx & 63;
        float s = lb2[d];
        #pragma unroll 8
        for (int k = 0; k < 64; k++) s += lz[t * 64 + k] * lw2[k * 64 + d];
        ly[idx] = s * (1.f / 9.f);
    }
    __syncthreads();
    for (int idx = tid; idx < 1056; idx += 256) {
        int e = idx / 33, t = idx - e * 33;
        float s = lpb[e];
        #pragma unroll 8
        for (int d = 0; d < 64; d++) s += ly[t * 64 + d] * lpw[d * 32 + e];
        out[(size_t)b * 1056 + idx] = s;
    }
}

// ---------------------------------------------------------------------------
extern "C" void kernel_launch(void* const* d_in, const int* in_sizes, int n_in,
                              void* d_out, int out_size, void* d_ws, size_t ws_size,
                              hipStream_t stream)
{
    const float* x = (const float*)d_in[0];
    const float* cw[6]; const float* cb[6]; const float* gg[6]; const float* gb[6];
    for (int l = 0; l < 6; l++) {
        cw[l] = (const float*)d_in[1 + 4 * l];
        cb[l] = (const float*)d_in[2 + 4 * l];
        gg[l] = (const float*)d_in[3 + 4 * l];
        gb[l] = (const float*)d_in[4 + 4 * l];
    }
    const float* ro_w = (const float*)d_in[25];
    const float* ro_b = (const float*)d_in[26];
    const float* mw0  = (const float*)d_in[27];
    const float* mb0  = (const float*)d_in[28];
    const float* mw1  = (const float*)d_in[29];
    const float* mb1  = (const float*)d_in[30];
    const float* rw1  = (const float*)d_in[31];
    const float* rb1  = (const float*)d_in[32];
    const float* rw2  = (const float*)d_in[33];
    const float* rb2  = (const float*)d_in[34];
    const float* pw   = (const float*)d_in[35];
    const float* pb   = (const float*)d_in[36];

    // ---- workspace layout (total ~111 MB) ----
    char* ws = (char*)d_ws;
    const size_t R1 = 0;           // 37,158,912 B : h1 chunk / h3 / h5
    const size_t R2 = 37158912;    // 74,022,912 B : h2 / h4 / lat buffers
    const size_t R3 = 111181824;   // stats
    bf16* h1c = (bf16*)(ws + R1);  // [144][256][501]
    bf16* h3  = (bf16*)(ws + R1);  // [576][256][126]
    bf16* h5  = (bf16*)(ws + R1);  // [576][64][33]
    bf16* h2  = (bf16*)(ws + R2);  // [576][256][251]
    bf16* h4  = (bf16*)(ws + R2);  // [576][256][64]
    float* latA  = (float*)(ws + R2);          // [576][33][64] (after convs done)
    float* latB  = latA  + 1216512;
    float* Aarr  = latB  + 1216512;
    float* Bvarr = Aarr  + 1216512;
    float* stat  = (float*)(ws + R3);
    float* mu0   = stat;          float* rstd0 = stat + 576;
    float* ssumA = stat + 1152;   // 5 layers x 576 sums then 5 x 576 sq
    float* ssqA  = ssumA + 5 * 576;
    float* muA   = ssqA + 5 * 576;
    float* rstdA = muA + 5 * 576;
    #define SSUM(l) (ssumA + ((l) - 1) * 576)
    #define SSQ(l)  (ssqA  + ((l) - 1) * 576)
    #define MU(l)   (muA   + ((l) - 1) * 576)
    #define RSTD(l) (rstdA + ((l) - 1) * 576)

    // zero the atomic stat accumulators (ws is poisoned before every call)
    zero_k<<<(5760 + 255) / 256, 256, 0, stream>>>(ssumA, 2 * 5 * 576);

    // ---- layer 0 stats (h0 never materialized) ----
    conv0_stats_k<<<576, 256, 0, stream>>>(x, cw[0], cb[0], mu0, rstd0);

    // ---- layers 1+2, chunked by 144 nodes ----
    for (int c = 0; c < 4; c++) {
        int n0 = c * 144;
        conv1_fused_k<<<dim3(4, 16, 144), 256, 0, stream>>>(
            x, cw[0], cb[0], gg[0], gb[0], mu0, rstd0, cw[1], cb[1],
            h1c, SSUM(1), SSQ(1), n0);
        gn_stats_k<<<1, 256, 0, stream>>>(SSUM(1) + n0, SSQ(1) + n0, MU(1) + n0, RSTD(1) + n0,
                                          1.f / (256.f * 501.f), 144);
        unsigned tot1 = 144u * 256u * 501u;
        gn_gelu_k<<<(tot1 + 255) / 256, 256, 0, stream>>>(h1c, MU(1) + n0, RSTD(1) + n0,
                                                          gg[1], gb[1], 256, 501, tot1);
        conv_s2_k<<<dim3(4, 8, 144), 256, 0, stream>>>(
            h1c, cw[2], cb[2], h2 + (size_t)n0 * 256 * 251,
            SSUM(2) + n0, SSQ(2) + n0, 256, 501, 251);
    }
    gn_stats_k<<<3, 256, 0, stream>>>(SSUM(2), SSQ(2), MU(2), RSTD(2), 1.f / (256.f * 251.f), 576);
    {
        unsigned tot = 576u * 256u * 251u;
        gn_gelu_k<<<(tot + 255) / 256, 256, 0, stream>>>(h2, MU(2), RSTD(2), gg[2], gb[2], 256, 251, tot);
    }

    // ---- layer 3 ----
    conv_s2_k<<<dim3(4, 4, 576), 256, 0, stream>>>(h2, cw[3], cb[3], h3, SSUM(3), SSQ(3), 256, 251, 126);
    gn_stats_k<<<3, 256, 0, stream>>>(SSUM(3), SSQ(3), MU(3), RSTD(3), 1.f / (256.f * 126.f), 576);
    {
        unsigned tot = 576u * 256u * 126u;
        gn_gelu_k<<<(tot + 255) / 256, 256, 0, stream>>>(h3, MU(3), RSTD(3), gg[3], gb[3], 256, 126, tot);
    }
    // ---- layer 4 ----
    conv_s2_k<<<dim3(4, 2, 576), 256, 0, stream>>>(h3, cw[4], cb[4], h4, SSUM(4), SSQ(4), 256, 126, 64);
    gn_stats_k<<<3, 256, 0, stream>>>(SSUM(4), SSQ(4), MU(4), RSTD(4), 1.f / (256.f * 64.f), 576);
    {
        unsigned tot = 576u * 256u * 64u;
        gn_gelu_k<<<(tot + 255) / 256, 256, 0, stream>>>(h4, MU(4), RSTD(4), gg[4], gb[4], 256, 64, tot);
    }
    // ---- layer 5 ----
    conv_s2_k<<<dim3(1, 2, 576), 256, 0, stream>>>(h4, cw[5], cb[5], h5, SSUM(5), SSQ(5), 64, 64, 33);
    gn_stats_k<<<3, 256, 0, stream>>>(SSUM(5), SSQ(5), MU(5), RSTD(5), 1.f / (64.f * 33.f), 576);
    {
        unsigned tot = 576u * 64u * 33u;
        gn_gelu_k<<<(tot + 255) / 256, 256, 0, stream>>>(h5, MU(5), RSTD(5), gg[5], gb[5], 64, 33, tot);
    }

    // ---- readout + message passing + head ----
    readout_k<<<576, 256, 0, stream>>>(h5, ro_w, ro_b, latA);
    msg_pre_k<<<576, 256, 0, stream>>>(latA, mw0, mb0, Aarr, Bvarr);
    msg_comb_k<<<576, 256, 0, stream>>>(latA, Aarr, Bvarr, latB);
    msg_pre_k<<<576, 256, 0, stream>>>(latB, mw1, mb1, Aarr, Bvarr);
    msg_comb_k<<<576, 256, 0, stream>>>(latB, Aarr, Bvarr, latA);
    final_k<<<64, 256, 0, stream>>>(latA, rw1, rb1, rw2, rb2, pw, pb, (float*)d_out);
}

// Round 3
// 1753.820 us; speedup vs baseline: 3.2765x; 3.2765x over previous
//
#include <hip/hip_runtime.h>
#include <hip/hip_bf16.h>

typedef __hip_bfloat16 bf16;
typedef __attribute__((ext_vector_type(8))) short s8v;   // 8 bf16 (A/B frag)
typedef __attribute__((ext_vector_type(4))) float f4v;   // 4 f32 (C/D frag)

__device__ __forceinline__ float gelu_f(float v) {
    return 0.5f * v * (1.f + erff(v * 0.70710678118654752440f));
}
__device__ __forceinline__ unsigned short f2bf_u(float f) {
    bf16 b = __float2bfloat16(f);
    return *(unsigned short*)&b;
}

// ---------------------------------------------------------------------------
__global__ __launch_bounds__(256) void zero_k(float* __restrict__ p, int n) {
    int i = blockIdx.x * 256 + threadIdx.x;
    if (i < n) p[i] = 0.f;
}

// ---------------------------------------------------------------------------
// GN stats of conv0 output (h0 never stored). One block per node.
// ---------------------------------------------------------------------------
__global__ __launch_bounds__(256) void conv0_stats_k(
    const float* __restrict__ x, const float* __restrict__ W0,
    const float* __restrict__ b0, float* __restrict__ mu0, float* __restrict__ rstd0)
{
    __shared__ float xsl[3008];
    __shared__ float ws[768];
    __shared__ float bs[256];
    __shared__ float red[512];
    const int n = blockIdx.x, tid = threadIdx.x;
    for (int i = tid; i < 3000; i += 256) xsl[i + 1] = x[(size_t)n * 3000 + i];
    if (tid == 0) xsl[0] = 0.f;
    for (int i = tid; i < 768; i += 256) ws[i] = W0[i];
    bs[tid] = b0[tid];
    __syncthreads();
    const float w0 = ws[tid * 3], w1 = ws[tid * 3 + 1], w2 = ws[tid * 3 + 2], bb = bs[tid];
    float s = 0.f, q = 0.f;
    for (int t = 0; t < 1000; t++) {
        float v = w0 * xsl[3 * t] + w1 * xsl[3 * t + 1] + w2 * xsl[3 * t + 2] + bb;
        s += v; q += v * v;
    }
    red[tid] = s; red[256 + tid] = q;
    __syncthreads();
    for (int st = 128; st > 0; st >>= 1) {
        if (tid < st) { red[tid] += red[tid + st]; red[256 + tid] += red[256 + tid + st]; }
        __syncthreads();
    }
    if (tid == 0) {
        float m = red[0] * (1.f / 256000.f);
        float var = red[256] * (1.f / 256000.f) - m * m;
        mu0[n] = m;
        rstd0[n] = rsqrtf(var + 1e-5f);
    }
}

// ---------------------------------------------------------------------------
__global__ void gn_stats_k(const float* __restrict__ ssum, const float* __restrict__ ssq,
                           float* __restrict__ mu, float* __restrict__ rstd,
                           float invCT, int count)
{
    int i = blockIdx.x * blockDim.x + threadIdx.x;
    if (i < count) {
        float m = ssum[i] * invCT;
        float v = ssq[i] * invCT - m * m;
        mu[i] = m;
        rstd[i] = rsqrtf(v + 1e-5f);
    }
}

// ===========================================================================
// MFMA conv core. Stride-2/width-2/pad-1 conv == GEMM with K=512 (im2col is a
// pure deinterleave: Xim[t][2ci+kk] = h[ci][2t-1+kk]).
// Block = 256 threads = 4 waves in 2x2 (wm,wn); wave tile = (MW*16)co x (NW*16)t
// using mfma_f32_16x16x32_bf16. K chunked by 64 (32 ci).
// A tile: aT[MB][64] bf16 (row stride 72 = 144B, 16B-aligned, 2-way-bank free).
// B tile: xim[NB][64] bf16, same stride. Raw conv+bias output (bf16) + GN stat
// atomics; input transform (prev-layer GN affine + GELU) fused into staging.
// ===========================================================================

// ---- layer 1: input transform = conv0(x) -> GN0 affine -> GELU, recomputed ----
__global__ __launch_bounds__(256) void conv1_mfma_k(
    const float* __restrict__ x, const float* __restrict__ W0,
    const float* __restrict__ b0, const float* __restrict__ g0,
    const float* __restrict__ be0, const float* __restrict__ mu0,
    const float* __restrict__ rstd0, const float* __restrict__ W1,
    const float* __restrict__ b1, bf16* __restrict__ hout,
    float* __restrict__ ssum, float* __restrict__ ssq, int n0)
{
    constexpr int MB = 128, NB = 128;
    __shared__ bf16 aT[MB][72];
    __shared__ bf16 xim[NB][72];
    __shared__ float xs[768];
    __shared__ float w0s[768];
    __shared__ float acS[256], ccS[256], biasS[MB];
    __shared__ float red[512];
    const int z = blockIdx.y;
    const int n = n0 + z;
    const int t0  = blockIdx.x * NB;
    const int co0 = blockIdx.z * MB;
    const int tid = threadIdx.x;
    for (int i = tid; i < 768; i += 256) {
        int xg = 6 * t0 - 4 + i;
        xs[i]  = (xg >= 0 && xg < 3000) ? x[(size_t)n * 3000 + xg] : 0.f;
        w0s[i] = W0[i];
    }
    {
        float mu = mu0[n], rs = rstd0[n];
        float a = rs * g0[tid];
        acS[tid] = a;
        ccS[tid] = (b0[tid] - mu) * a + be0[tid];
        if (tid < MB) biasS[tid] = b1[co0 + tid];
    }
    __syncthreads();
    const int w = tid >> 6, lane = tid & 63;
    const int wm = w & 1, wn = w >> 1;
    const int l16 = lane & 15, quad = lane >> 4;
    f4v acc[4][4];
    #pragma unroll
    for (int i = 0; i < 4; i++)
        #pragma unroll
        for (int j = 0; j < 4; j++) acc[i][j] = (f4v){0.f, 0.f, 0.f, 0.f};

    for (int ci0 = 0; ci0 < 256; ci0 += 32) {
        // A staging: fp32 W1 -> bf16 LDS, [m][k] k-contig. float4 loads, b64 writes.
        for (int e = tid; e < MB * 16; e += 256) {
            int m = e >> 4, kq = e & 15;
            float4 wv = *(const float4*)&W1[(size_t)(co0 + m) * 512 + ci0 * 2 + 4 * kq];
            ushort4 pk = {f2bf_u(wv.x), f2bf_u(wv.y), f2bf_u(wv.z), f2bf_u(wv.w)};
            *(ushort4*)&aT[m][4 * kq] = pk;
        }
        // B staging: compute conv0->GN0->GELU on the fly (ci2-major: xs broadcast,
        // conflict-free xim writes).
        for (int e = tid; e < 16 * NB; e += 256) {
            int ci2 = e & 15, p = e >> 4;
            int ci = ci0 + 2 * ci2;
            int q0 = 2 * p;
            int tin0 = 2 * t0 - 1 + q0;
            float x00 = xs[3*q0],   x01 = xs[3*q0+1], x02 = xs[3*q0+2];
            float x10 = xs[3*q0+3], x11 = xs[3*q0+4], x12 = xs[3*q0+5];
            float v[4] = {0.f, 0.f, 0.f, 0.f};
            #pragma unroll
            for (int s = 0; s < 2; s++) {
                int cc = ci + s;
                float wa = w0s[3*cc], wb = w0s[3*cc+1], wc = w0s[3*cc+2];
                float a = acS[cc], c = ccS[cc];
                if (tin0 >= 0 && tin0 < 1000) v[2*s]   = gelu_f((wa*x00 + wb*x01 + wc*x02) * a + c);
                if (tin0 + 1 < 1000)          v[2*s+1] = gelu_f((wa*x10 + wb*x11 + wc*x12) * a + c);
            }
            ushort4 pk = {f2bf_u(v[0]), f2bf_u(v[1]), f2bf_u(v[2]), f2bf_u(v[3])};
            *(ushort4*)&xim[p][4 * ci2] = pk;
        }
        __syncthreads();
        #pragma unroll
        for (int ks = 0; ks < 2; ks++) {
            s8v af[4], bfr[4];
            #pragma unroll
            for (int i = 0; i < 4; i++)
                af[i] = *(const s8v*)&aT[wm * 64 + i * 16 + l16][ks * 32 + quad * 8];
            #pragma unroll
            for (int j = 0; j < 4; j++)
                bfr[j] = *(const s8v*)&xim[wn * 64 + j * 16 + l16][ks * 32 + quad * 8];
            #pragma unroll
            for (int i = 0; i < 4; i++)
                #pragma unroll
                for (int j = 0; j < 4; j++)
                    acc[i][j] = __builtin_amdgcn_mfma_f32_16x16x32_bf16(af[i], bfr[j], acc[i][j], 0, 0, 0);
        }
        __syncthreads();
    }
    float lsum = 0.f, lsq = 0.f;
    #pragma unroll
    for (int i = 0; i < 4; i++) {
        #pragma unroll
        for (int j = 0; j < 4; j++) {
            #pragma unroll
            for (int r = 0; r < 4; r++) {
                int col = co0 + wm * 64 + i * 16 + quad * 4 + r;
                int t   = t0 + wn * 64 + j * 16 + l16;
                if (t < 501) {
                    float v = acc[i][j][r] + biasS[col - co0];
                    hout[(size_t)z * 256 * 501 + (size_t)col * 501 + t] = __float2bfloat16(v);
                    lsum += v; lsq += v * v;
                }
            }
        }
    }
    red[tid] = lsum; red[256 + tid] = lsq;
    __syncthreads();
    for (int st = 128; st > 0; st >>= 1) {
        if (tid < st) { red[tid] += red[tid + st]; red[256 + tid] += red[256 + tid + st]; }
        __syncthreads();
    }
    if (tid == 0) { atomicAdd(&ssum[n], red[0]); atomicAdd(&ssq[n], red[256]); }
}

// ---- layers 2..5: input transform = GN affine + GELU on raw bf16 input ----
template<int MW, int NW>
__global__ __launch_bounds__(256) void convN_mfma_k(
    const bf16* __restrict__ hin, const float* __restrict__ W,
    const float* __restrict__ bias, const float* __restrict__ g_in,
    const float* __restrict__ be_in, const float* __restrict__ mu_in,
    const float* __restrict__ rstd_in, bf16* __restrict__ hout,
    float* __restrict__ ssum, float* __restrict__ ssq,
    int T_in, int T_out, int CO, int n0)
{
    constexpr int MB = 2 * MW * 16;
    constexpr int NB = 2 * NW * 16;
    __shared__ bf16 aT[MB][72];
    __shared__ bf16 xim[NB][72];
    __shared__ float acS[256], ccS[256], biasS[MB];
    __shared__ float red[512];
    const int z = blockIdx.y;
    const int n = n0 + z;
    const int t0  = blockIdx.x * NB;
    const int co0 = blockIdx.z * MB;
    const int tid = threadIdx.x;
    {
        float mu = mu_in[n], rs = rstd_in[n];
        float a = rs * g_in[tid];
        acS[tid] = a;
        ccS[tid] = be_in[tid] - mu * a;
        for (int i = tid; i < MB; i += 256) biasS[i] = bias[co0 + i];
    }
    __syncthreads();
    const int w = tid >> 6, lane = tid & 63;
    const int wm = w & 1, wn = w >> 1;
    const int l16 = lane & 15, quad = lane >> 4;
    f4v acc[MW][NW];
    #pragma unroll
    for (int i = 0; i < MW; i++)
        #pragma unroll
        for (int j = 0; j < NW; j++) acc[i][j] = (f4v){0.f, 0.f, 0.f, 0.f};
    const bf16* xb = hin + (size_t)z * 256 * T_in;

    for (int ci0 = 0; ci0 < 256; ci0 += 32) {
        for (int e = tid; e < MB * 16; e += 256) {
            int m = e >> 4, kq = e & 15;
            float4 wv = *(const float4*)&W[(size_t)(co0 + m) * 512 + ci0 * 2 + 4 * kq];
            ushort4 pk = {f2bf_u(wv.x), f2bf_u(wv.y), f2bf_u(wv.z), f2bf_u(wv.w)};
            *(ushort4*)&aT[m][4 * kq] = pk;
        }
        // p-major: consecutive lanes -> consecutive tin (coalesced global loads)
        for (int e = tid; e < 16 * NB; e += 256) {
            int ci2 = e / NB, p = e % NB;
            int ci = ci0 + 2 * ci2;
            int tin0 = 2 * (t0 + p) - 1;
            float a0 = acS[ci], c0 = ccS[ci], a1 = acS[ci + 1], c1 = ccS[ci + 1];
            const bf16* r0 = xb + (size_t)ci * T_in;
            const bf16* r1 = r0 + T_in;
            float v00 = 0.f, v01 = 0.f, v10 = 0.f, v11 = 0.f;
            if (tin0 >= 0 && tin0 < T_in) {
                v00 = gelu_f(__bfloat162float(r0[tin0]) * a0 + c0);
                v10 = gelu_f(__bfloat162float(r1[tin0]) * a1 + c1);
            }
            if (tin0 + 1 < T_in) {
                v01 = gelu_f(__bfloat162float(r0[tin0 + 1]) * a0 + c0);
                v11 = gelu_f(__bfloat162float(r1[tin0 + 1]) * a1 + c1);
            }
            ushort4 pk = {f2bf_u(v00), f2bf_u(v01), f2bf_u(v10), f2bf_u(v11)};
            *(ushort4*)&xim[p][4 * ci2] = pk;
        }
        __syncthreads();
        #pragma unroll
        for (int ks = 0; ks < 2; ks++) {
            s8v af[MW], bfr[NW];
            #pragma unroll
            for (int i = 0; i < MW; i++)
                af[i] = *(const s8v*)&aT[wm * MW * 16 + i * 16 + l16][ks * 32 + quad * 8];
            #pragma unroll
            for (int j = 0; j < NW; j++)
                bfr[j] = *(const s8v*)&xim[wn * NW * 16 + j * 16 + l16][ks * 32 + quad * 8];
            #pragma unroll
            for (int i = 0; i < MW; i++)
                #pragma unroll
                for (int j = 0; j < NW; j++)
                    acc[i][j] = __builtin_amdgcn_mfma_f32_16x16x32_bf16(af[i], bfr[j], acc[i][j], 0, 0, 0);
        }
        __syncthreads();
    }
    float lsum = 0.f, lsq = 0.f;
    #pragma unroll
    for (int i = 0; i < MW; i++) {
        #pragma unroll
        for (int j = 0; j < NW; j++) {
            #pragma unroll
            for (int r = 0; r < 4; r++) {
                int col = co0 + wm * MW * 16 + i * 16 + quad * 4 + r;
                int t   = t0 + wn * NW * 16 + j * 16 + l16;
                if (t < T_out) {
                    float v = acc[i][j][r] + biasS[col - co0];
                    hout[(size_t)z * CO * T_out + (size_t)col * T_out + t] = __float2bfloat16(v);
                    lsum += v; lsq += v * v;
                }
            }
        }
    }
    red[tid] = lsum; red[256 + tid] = lsq;
    __syncthreads();
    for (int st = 128; st > 0; st >>= 1) {
        if (tid < st) { red[tid] += red[tid + st]; red[256 + tid] += red[256 + tid + st]; }
        __syncthreads();
    }
    if (tid == 0) { atomicAdd(&ssum[n], red[0]); atomicAdd(&ssq[n], red[256]); }
}

// ---------------------------------------------------------------------------
// Readout 1x1 with fused GN5+GELU: lat[n][t][d] = sum_c gelu(gn(h5[n][c][t]))*ro_w[c][d] + ro_b[d]
// ---------------------------------------------------------------------------
__global__ __launch_bounds__(256) void readout_gn_k(
    const bf16* __restrict__ h5, const float* __restrict__ row,
    const float* __restrict__ rob, const float* __restrict__ g5,
    const float* __restrict__ be5, const float* __restrict__ mu5,
    const float* __restrict__ rstd5, float* __restrict__ lat)
{
    __shared__ float lh[2112];   // [c][t] 64 x 33
    __shared__ float lw[4096];
    __shared__ float lb[64];
    const int n = blockIdx.x, tid = threadIdx.x;
    const float mu = mu5[n], rs = rstd5[n];
    for (int idx = tid; idx < 2112; idx += 256) {
        int c = idx / 33;
        float a = rs * g5[c];
        float v = __bfloat162float(h5[(size_t)n * 2112 + idx]) * a + (be5[c] - mu * a);
        lh[idx] = gelu_f(v);
    }
    for (int idx = tid; idx < 4096; idx += 256) lw[idx] = row[idx];
    if (tid < 64) lb[tid] = rob[tid];
    __syncthreads();
    for (int idx = tid; idx < 2112; idx += 256) {
        int t = idx >> 6, d = idx & 63;
        float a = lb[d];
        #pragma unroll 8
        for (int c = 0; c < 64; c++) a += lh[c * 33 + t] * lw[c * 64 + d];
        lat[(size_t)n * 2112 + idx] = a;   // [t][d]
    }
}

// ---------------------------------------------------------------------------
__global__ __launch_bounds__(256) void msg_pre_k(
    const float* __restrict__ lat, const float* __restrict__ W,
    const float* __restrict__ b, float* __restrict__ A, float* __restrict__ Bv)
{
    __shared__ float ll[2112];
    __shared__ float lw[8192];
    __shared__ float lb[64];
    const int n = blockIdx.x, tid = threadIdx.x;
    for (int idx = tid; idx < 2112; idx += 256) ll[idx] = lat[(size_t)n * 2112 + idx];
    for (int idx = tid; idx < 8192; idx += 256) lw[idx] = W[idx];
    if (tid < 64) lb[tid] = b[tid];
    __syncthreads();
    for (int idx = tid; idx < 2112; idx += 256) {
        int t = idx >> 6, d = idx & 63;
        float a = 0.f, bb = lb[d];
        #pragma unroll 8
        for (int k = 0; k < 64; k++) {
            float xv = ll[t * 64 + k];
            a  += xv * lw[k * 64 + d];
            bb += xv * lw[(64 + k) * 64 + d];
        }
        A[(size_t)n * 2112 + idx]  = a;
        Bv[(size_t)n * 2112 + idx] = bb;
    }
}

__global__ __launch_bounds__(256) void msg_comb_k(
    const float* __restrict__ latin, const float* __restrict__ A,
    const float* __restrict__ Bv, float* __restrict__ latout)
{
    const int n = blockIdx.x, tid = threadIdx.x;
    const int b9 = (n / 9) * 9, j = n - b9;
    for (int idx = tid; idx < 2112; idx += 256) {
        float base = Bv[(size_t)n * 2112 + idx];
        float s = 0.f;
        #pragma unroll
        for (int i = 0; i < 9; i++) {
            if (i == j) continue;
            float v = A[(size_t)(b9 + i) * 2112 + idx] + base;
            s += fmaxf(v, 0.f);
        }
        latout[(size_t)n * 2112 + idx] = latin[(size_t)n * 2112 + idx] + s * 0.125f;
    }
}

// ---------------------------------------------------------------------------
__global__ __launch_bounds__(256) void final_k(
    const float* __restrict__ lat,
    const float* __restrict__ w1, const float* __restrict__ b1,
    const float* __restrict__ w2, const float* __restrict__ b2,
    const float* __restrict__ pw, const float* __restrict__ pb,
    float* __restrict__ out)
{
    __shared__ float ly[2112], lz[2112];
    __shared__ float lw1[4096], lw2[4096], lpw[2048];
    __shared__ float lb1[64], lb2[64], lpb[32];
    const int b = blockIdx.x, tid = threadIdx.x;
    for (int idx = tid; idx < 4096; idx += 256) { lw1[idx] = w1[idx]; lw2[idx] = w2[idx]; }
    for (int idx = tid; idx < 2048; idx += 256) lpw[idx] = pw[idx];
    if (tid < 64) { lb1[tid] = b1[tid]; lb2[tid] = b2[tid]; }
    if (tid < 32) lpb[tid] = pb[tid];
    for (int idx = tid; idx < 2112; idx += 256) {
        float s = 0.f;
        #pragma unroll
        for (int jj = 0; jj < 9; jj++) s += lat[((size_t)b * 9 + jj) * 2112 + idx];
        ly[idx] = s;
    }
    __syncthreads();
    for (int idx = tid; idx < 2112; idx += 256) {
        int t = idx >> 6, d = idx & 63;
        float s = lb1[d];
        #pragma unroll 8
        for (int k = 0; k < 64; k++) s += ly[t * 64 + k] * lw1[k * 64 + d];
        lz[idx] = fmaxf(s, 0.f);
    }
    __syncthreads();
    for (int idx = tid; idx < 2112; idx += 256) {
        int t = idx >> 6, d = idx & 63;
        float s = lb2[d];
        #pragma unroll 8
        for (int k = 0; k < 64; k++) s += lz[t * 64 + k] * lw2[k * 64 + d];
        ly[idx] = s * (1.f / 9.f);
    }
    __syncthreads();
    for (int idx = tid; idx < 1056; idx += 256) {
        int e = idx / 33, t = idx - e * 33;
        float s = lpb[e];
        #pragma unroll 8
        for (int d = 0; d < 64; d++) s += ly[t * 64 + d] * lpw[d * 32 + e];
        out[(size_t)b * 1056 + idx] = s;
    }
}

// ---------------------------------------------------------------------------
extern "C" void kernel_launch(void* const* d_in, const int* in_sizes, int n_in,
                              void* d_out, int out_size, void* d_ws, size_t ws_size,
                              hipStream_t stream)
{
    const float* x = (const float*)d_in[0];
    const float* cw[6]; const float* cb[6]; const float* gg[6]; const float* gb[6];
    for (int l = 0; l < 6; l++) {
        cw[l] = (const float*)d_in[1 + 4 * l];
        cb[l] = (const float*)d_in[2 + 4 * l];
        gg[l] = (const float*)d_in[3 + 4 * l];
        gb[l] = (const float*)d_in[4 + 4 * l];
    }
    const float* ro_w = (const float*)d_in[25];
    const float* ro_b = (const float*)d_in[26];
    const float* mw0  = (const float*)d_in[27];
    const float* mb0  = (const float*)d_in[28];
    const float* mw1  = (const float*)d_in[29];
    const float* mb1  = (const float*)d_in[30];
    const float* rw1  = (const float*)d_in[31];
    const float* rb1  = (const float*)d_in[32];
    const float* rw2  = (const float*)d_in[33];
    const float* rb2  = (const float*)d_in[34];
    const float* pw   = (const float*)d_in[35];
    const float* pb   = (const float*)d_in[36];

    // ---- workspace layout (identical peak to the passing round-1: ~111.2 MB) ----
    char* ws = (char*)d_ws;
    const size_t R1 = 0;           // 37,158,912 B : h1 chunk / h3 / h5
    const size_t R2 = 37158912;    // 74,022,912 B : h2 / h4 / lat buffers
    const size_t R3 = 111181824;   // stats
    bf16* h1c = (bf16*)(ws + R1);  // [144][256][501]
    bf16* h3  = (bf16*)(ws + R1);  // [576][256][126]
    bf16* h5  = (bf16*)(ws + R1);  // [576][64][33]
    bf16* h2  = (bf16*)(ws + R2);  // [576][256][251]
    bf16* h4  = (bf16*)(ws + R2);  // [576][256][64]
    float* latA  = (float*)(ws + R2);
    float* latB  = latA  + 1216512;
    float* Aarr  = latB  + 1216512;
    float* Bvarr = Aarr  + 1216512;
    float* stat  = (float*)(ws + R3);
    float* mu0   = stat;          float* rstd0 = stat + 576;
    float* ssumA = stat + 1152;
    float* ssqA  = ssumA + 5 * 576;
    float* muA   = ssqA + 5 * 576;
    float* rstdA = muA + 5 * 576;
    #define SSUM(l) (ssumA + ((l) - 1) * 576)
    #define SSQ(l)  (ssqA  + ((l) - 1) * 576)
    #define MU(l)   (muA   + ((l) - 1) * 576)
    #define RSTD(l) (rstdA + ((l) - 1) * 576)

    zero_k<<<(5760 + 255) / 256, 256, 0, stream>>>(ssumA, 2 * 5 * 576);
    conv0_stats_k<<<576, 256, 0, stream>>>(x, cw[0], cb[0], mu0, rstd0);

    // ---- layers 1+2, chunked by 144 nodes (footprint) ----
    for (int c = 0; c < 4; c++) {
        int n0 = c * 144;
        conv1_mfma_k<<<dim3(4, 144, 2), 256, 0, stream>>>(
            x, cw[0], cb[0], gg[0], gb[0], mu0, rstd0, cw[1], cb[1],
            h1c, SSUM(1), SSQ(1), n0);
        gn_stats_k<<<1, 256, 0, stream>>>(SSUM(1) + n0, SSQ(1) + n0, MU(1) + n0, RSTD(1) + n0,
                                          1.f / (256.f * 501.f), 144);
        convN_mfma_k<4, 4><<<dim3(2, 144, 2), 256, 0, stream>>>(
            h1c, cw[2], cb[2], gg[1], gb[1], MU(1), RSTD(1),
            h2 + (size_t)n0 * 256 * 251, SSUM(2), SSQ(2), 501, 251, 256, n0);
    }
    gn_stats_k<<<3, 256, 0, stream>>>(SSUM(2), SSQ(2), MU(2), RSTD(2), 1.f / (256.f * 251.f), 576);

    // ---- layer 3 ----
    convN_mfma_k<4, 4><<<dim3(1, 576, 2), 256, 0, stream>>>(
        h2, cw[3], cb[3], gg[2], gb[2], MU(2), RSTD(2), h3, SSUM(3), SSQ(3), 251, 126, 256, 0);
    gn_stats_k<<<3, 256, 0, stream>>>(SSUM(3), SSQ(3), MU(3), RSTD(3), 1.f / (256.f * 126.f), 576);

    // ---- layer 4 ----
    convN_mfma_k<4, 2><<<dim3(1, 576, 2), 256, 0, stream>>>(
        h3, cw[4], cb[4], gg[3], gb[3], MU(3), RSTD(3), h4, SSUM(4), SSQ(4), 126, 64, 256, 0);
    gn_stats_k<<<3, 256, 0, stream>>>(SSUM(4), SSQ(4), MU(4), RSTD(4), 1.f / (256.f * 64.f), 576);

    // ---- layer 5 ----
    convN_mfma_k<2, 2><<<dim3(1, 576, 1), 256, 0, stream>>>(
        h4, cw[5], cb[5], gg[4], gb[4], MU(4), RSTD(4), h5, SSUM(5), SSQ(5), 64, 33, 64, 0);
    gn_stats_k<<<3, 256, 0, stream>>>(SSUM(5), SSQ(5), MU(5), RSTD(5), 1.f / (64.f * 33.f), 576);

    // ---- readout (fused GN5+GELU) + message passing + head ----
    readout_gn_k<<<576, 256, 0, stream>>>(h5, ro_w, ro_b, gg[5], gb[5], MU(5), RSTD(5), latA);
    msg_pre_k<<<576, 256, 0, stream>>>(latA, mw0, mb0, Aarr, Bvarr);
    msg_comb_k<<<576, 256, 0, stream>>>(latA, Aarr, Bvarr, latB);
    msg_pre_k<<<576, 256, 0, stream>>>(latB, mw1, mb1, Aarr, Bvarr);
    msg_comb_k<<<576, 256, 0, stream>>>(latB, Aarr, Bvarr, latA);
    final_k<<<64, 256, 0, stream>>>(latA, rw1, rb1, rw2, rb2, pw, pb, (float*)d_out);
}

// Round 4
// 1402.921 us; speedup vs baseline: 4.0960x; 1.2501x over previous
//
#include <hip/hip_runtime.h>
#include <hip/hip_bf16.h>

typedef __hip_bfloat16 bf16;
typedef __attribute__((ext_vector_type(8))) short s8v;   // 8 bf16 (A/B frag)
typedef __attribute__((ext_vector_type(4))) float f4v;   // 4 f32 (C/D frag)

// Branch-free erf (Abramowitz-Stegun 7.1.26), |abs err| < 1.5e-7 — exact at
// bf16 resolution, no divergence (vs libm erff's multi-range branches).
__device__ __forceinline__ float erf_approx(float x) {
    float ax = fabsf(x);
    float t = 1.0f / (1.0f + 0.3275911f * ax);
    float p = t * (0.254829592f + t * (-0.284496736f + t * (1.421413741f
              + t * (-1.453152027f + t * 1.061405429f))));
    float r = 1.0f - p * __expf(-ax * ax);
    return copysignf(r, x);
}
__device__ __forceinline__ float gelu_f(float v) {
    return 0.5f * v * (1.f + erf_approx(v * 0.70710678118654752440f));
}
__device__ __forceinline__ unsigned short f2bf_u(float f) {
    bf16 b = __float2bfloat16(f);
    return *(unsigned short*)&b;
}

// ---------------------------------------------------------------------------
__global__ __launch_bounds__(256) void zero_k(float* __restrict__ p, int n) {
    int i = blockIdx.x * 256 + threadIdx.x;
    if (i < n) p[i] = 0.f;
}

// ---------------------------------------------------------------------------
// GN stats of conv0 output (h0 never stored). One block per node.
// ---------------------------------------------------------------------------
__global__ __launch_bounds__(256) void conv0_stats_k(
    const float* __restrict__ x, const float* __restrict__ W0,
    const float* __restrict__ b0, float* __restrict__ mu0, float* __restrict__ rstd0)
{
    __shared__ float xsl[3008];
    __shared__ float ws[768];
    __shared__ float bs[256];
    __shared__ float red[512];
    const int n = blockIdx.x, tid = threadIdx.x;
    for (int i = tid; i < 3000; i += 256) xsl[i + 1] = x[(size_t)n * 3000 + i];
    if (tid == 0) xsl[0] = 0.f;
    for (int i = tid; i < 768; i += 256) ws[i] = W0[i];
    bs[tid] = b0[tid];
    __syncthreads();
    const float w0 = ws[tid * 3], w1 = ws[tid * 3 + 1], w2 = ws[tid * 3 + 2], bb = bs[tid];
    float s = 0.f, q = 0.f;
    for (int t = 0; t < 1000; t++) {
        float v = w0 * xsl[3 * t] + w1 * xsl[3 * t + 1] + w2 * xsl[3 * t + 2] + bb;
        s += v; q += v * v;
    }
    red[tid] = s; red[256 + tid] = q;
    __syncthreads();
    for (int st = 128; st > 0; st >>= 1) {
        if (tid < st) { red[tid] += red[tid + st]; red[256 + tid] += red[256 + tid + st]; }
        __syncthreads();
    }
    if (tid == 0) {
        float m = red[0] * (1.f / 256000.f);
        float var = red[256] * (1.f / 256000.f) - m * m;
        mu0[n] = m;
        rstd0[n] = rsqrtf(var + 1e-5f);
    }
}

// ---------------------------------------------------------------------------
__global__ void gn_stats_k(const float* __restrict__ ssum, const float* __restrict__ ssq,
                           float* __restrict__ mu, float* __restrict__ rstd,
                           float invCT, int count)
{
    int i = blockIdx.x * blockDim.x + threadIdx.x;
    if (i < count) {
        float m = ssum[i] * invCT;
        float v = ssq[i] * invCT - m * m;
        mu[i] = m;
        rstd[i] = rsqrtf(v + 1e-5f);
    }
}

// ===========================================================================
// MFMA conv: stride-2/width-2/pad-1 conv == GEMM K=512 (im2col = pure
// deinterleave). One block covers ALL output channels (MB = 64*MW via 4 waves
// along co) x NB=NW*16 t. Input transform (prev GN affine + GELU) fused into
// B staging; raw conv+bias out (bf16) + GN stat atomics.
// ===========================================================================
template<int MW, int NW>
__global__ __launch_bounds__(256, 2) void convN_mfma_k(
    const bf16* __restrict__ hin, const float* __restrict__ W,
    const float* __restrict__ bias, const float* __restrict__ g_in,
    const float* __restrict__ be_in, const float* __restrict__ mu_in,
    const float* __restrict__ rstd_in, bf16* __restrict__ hout,
    float* __restrict__ ssum, float* __restrict__ ssq,
    int T_in, int T_out)
{
    constexpr int MB = MW * 64;   // == CO
    constexpr int NB = NW * 16;
    __shared__ bf16 aT[MB][72];
    __shared__ bf16 xim[NB][72];
    __shared__ float acS[256], ccS[256], biasS[MB];
    __shared__ float red[512];
    const int n  = blockIdx.y;
    const int t0 = blockIdx.x * NB;
    const int tid = threadIdx.x;
    {
        float mu = mu_in[n], rs = rstd_in[n];
        float a = rs * g_in[tid];
        acS[tid] = a;
        ccS[tid] = be_in[tid] - mu * a;
        for (int i = tid; i < MB; i += 256) biasS[i] = bias[i];
    }
    __syncthreads();
    const int w = tid >> 6, lane = tid & 63;
    const int l16 = lane & 15, quad = lane >> 4;
    f4v acc[MW][NW];
    #pragma unroll
    for (int i = 0; i < MW; i++)
        #pragma unroll
        for (int j = 0; j < NW; j++) acc[i][j] = (f4v){0.f, 0.f, 0.f, 0.f};
    const bf16* xb = hin + (size_t)n * 256 * T_in;

    for (int ci0 = 0; ci0 < 256; ci0 += 32) {
        // A: fp32 W -> bf16 LDS, [m][k] k-contig
        for (int e = tid; e < MB * 16; e += 256) {
            int m = e >> 4, kq = e & 15;
            float4 wv = *(const float4*)&W[(size_t)m * 512 + ci0 * 2 + 4 * kq];
            ushort4 pk = {f2bf_u(wv.x), f2bf_u(wv.y), f2bf_u(wv.z), f2bf_u(wv.w)};
            *(ushort4*)&aT[m][4 * kq] = pk;
        }
        // B: p-minor (coalesced loads), fused GN-affine + GELU
        for (int e = tid; e < NB * 16; e += 256) {
            int ci2 = e / NB, p = e % NB;
            int ci = ci0 + 2 * ci2;
            int tin0 = 2 * (t0 + p) - 1;
            float a0 = acS[ci], c0 = ccS[ci], a1 = acS[ci + 1], c1 = ccS[ci + 1];
            const bf16* r0 = xb + (size_t)ci * T_in;
            const bf16* r1 = r0 + T_in;
            float v00 = 0.f, v01 = 0.f, v10 = 0.f, v11 = 0.f;
            if (tin0 >= 0 && tin0 < T_in) {
                v00 = gelu_f(__bfloat162float(r0[tin0]) * a0 + c0);
                v10 = gelu_f(__bfloat162float(r1[tin0]) * a1 + c1);
            }
            if (tin0 + 1 < T_in) {
                v01 = gelu_f(__bfloat162float(r0[tin0 + 1]) * a0 + c0);
                v11 = gelu_f(__bfloat162float(r1[tin0 + 1]) * a1 + c1);
            }
            ushort4 pk = {f2bf_u(v00), f2bf_u(v01), f2bf_u(v10), f2bf_u(v11)};
            *(ushort4*)&xim[p][4 * ci2] = pk;
        }
        __syncthreads();
        #pragma unroll
        for (int ks = 0; ks < 2; ks++) {
            s8v af[MW], bfr[NW];
            #pragma unroll
            for (int i = 0; i < MW; i++)
                af[i] = *(const s8v*)&aT[w * MW * 16 + i * 16 + l16][ks * 32 + quad * 8];
            #pragma unroll
            for (int j = 0; j < NW; j++)
                bfr[j] = *(const s8v*)&xim[j * 16 + l16][ks * 32 + quad * 8];
            #pragma unroll
            for (int i = 0; i < MW; i++)
                #pragma unroll
                for (int j = 0; j < NW; j++)
                    acc[i][j] = __builtin_amdgcn_mfma_f32_16x16x32_bf16(af[i], bfr[j], acc[i][j], 0, 0, 0);
        }
        __syncthreads();
    }
    float lsum = 0.f, lsq = 0.f;
    #pragma unroll
    for (int i = 0; i < MW; i++) {
        #pragma unroll
        for (int j = 0; j < NW; j++) {
            #pragma unroll
            for (int r = 0; r < 4; r++) {
                int col = w * MW * 16 + i * 16 + quad * 4 + r;
                int t   = t0 + j * 16 + l16;
                if (t < T_out) {
                    float v = acc[i][j][r] + biasS[col];
                    hout[(size_t)n * MB * T_out + (size_t)col * T_out + t] = __float2bfloat16(v);
                    lsum += v; lsq += v * v;
                }
            }
        }
    }
    red[tid] = lsum; red[256 + tid] = lsq;
    __syncthreads();
    for (int st = 128; st > 0; st >>= 1) {
        if (tid < st) { red[tid] += red[tid + st]; red[256 + tid] += red[256 + tid + st]; }
        __syncthreads();
    }
    if (tid == 0) { atomicAdd(&ssum[n], red[0]); atomicAdd(&ssq[n], red[256]); }
}

// ---- layer 1: B staging recomputes conv0 -> GN0 affine -> GELU from x ----
__global__ __launch_bounds__(256, 2) void conv1_mfma_k(
    const float* __restrict__ x, const float* __restrict__ W0,
    const float* __restrict__ b0, const float* __restrict__ g0,
    const float* __restrict__ be0, const float* __restrict__ mu0,
    const float* __restrict__ rstd0, const float* __restrict__ W1,
    const float* __restrict__ b1, bf16* __restrict__ hout,
    float* __restrict__ ssum, float* __restrict__ ssq)
{
    constexpr int MW = 4, NW = 8;
    constexpr int MB = 256, NB = 128;
    __shared__ bf16 aT[MB][72];
    __shared__ bf16 xim[NB][72];
    __shared__ float xs[768];
    __shared__ float w0s[768];
    __shared__ float acS[256], ccS[256], biasS[MB];
    __shared__ float red[512];
    const int n  = blockIdx.y;
    const int t0 = blockIdx.x * NB;
    const int tid = threadIdx.x;
    for (int i = tid; i < 768; i += 256) {
        int xg = 6 * t0 - 4 + i;
        xs[i]  = (xg >= 0 && xg < 3000) ? x[(size_t)n * 3000 + xg] : 0.f;
        w0s[i] = W0[i];
    }
    {
        float mu = mu0[n], rs = rstd0[n];
        float a = rs * g0[tid];
        acS[tid] = a;
        ccS[tid] = (b0[tid] - mu) * a + be0[tid];
        biasS[tid] = b1[tid];
    }
    __syncthreads();
    const int w = tid >> 6, lane = tid & 63;
    const int l16 = lane & 15, quad = lane >> 4;
    f4v acc[MW][NW];
    #pragma unroll
    for (int i = 0; i < MW; i++)
        #pragma unroll
        for (int j = 0; j < NW; j++) acc[i][j] = (f4v){0.f, 0.f, 0.f, 0.f};

    for (int ci0 = 0; ci0 < 256; ci0 += 32) {
        for (int e = tid; e < MB * 16; e += 256) {
            int m = e >> 4, kq = e & 15;
            float4 wv = *(const float4*)&W1[(size_t)m * 512 + ci0 * 2 + 4 * kq];
            ushort4 pk = {f2bf_u(wv.x), f2bf_u(wv.y), f2bf_u(wv.z), f2bf_u(wv.w)};
            *(ushort4*)&aT[m][4 * kq] = pk;
        }
        // ci2-minor (xs broadcast reads, conflict-light xim writes)
        for (int e = tid; e < NB * 16; e += 256) {
            int ci2 = e & 15, p = e >> 4;
            int ci = ci0 + 2 * ci2;
            int q0 = 2 * p;
            int tin0 = 2 * (t0 + p) - 1;
            float x00 = xs[3*q0],   x01 = xs[3*q0+1], x02 = xs[3*q0+2];
            float x10 = xs[3*q0+3], x11 = xs[3*q0+4], x12 = xs[3*q0+5];
            float v[4] = {0.f, 0.f, 0.f, 0.f};
            #pragma unroll
            for (int s = 0; s < 2; s++) {
                int cc = ci + s;
                float wa = w0s[3*cc], wb = w0s[3*cc+1], wc = w0s[3*cc+2];
                float a = acS[cc], c = ccS[cc];
                if (tin0 >= 0 && tin0 < 1000) v[2*s]   = gelu_f((wa*x00 + wb*x01 + wc*x02) * a + c);
                if (tin0 + 1 < 1000)          v[2*s+1] = gelu_f((wa*x10 + wb*x11 + wc*x12) * a + c);
            }
            ushort4 pk = {f2bf_u(v[0]), f2bf_u(v[1]), f2bf_u(v[2]), f2bf_u(v[3])};
            *(ushort4*)&xim[p][4 * ci2] = pk;
        }
        __syncthreads();
        #pragma unroll
        for (int ks = 0; ks < 2; ks++) {
            s8v af[MW], bfr[NW];
            #pragma unroll
            for (int i = 0; i < MW; i++)
                af[i] = *(const s8v*)&aT[w * MW * 16 + i * 16 + l16][ks * 32 + quad * 8];
            #pragma unroll
            for (int j = 0; j < NW; j++)
                bfr[j] = *(const s8v*)&xim[j * 16 + l16][ks * 32 + quad * 8];
            #pragma unroll
            for (int i = 0; i < MW; i++)
                #pragma unroll
                for (int j = 0; j < NW; j++)
                    acc[i][j] = __builtin_amdgcn_mfma_f32_16x16x32_bf16(af[i], bfr[j], acc[i][j], 0, 0, 0);
        }
        __syncthreads();
    }
    float lsum = 0.f, lsq = 0.f;
    #pragma unroll
    for (int i = 0; i < MW; i++) {
        #pragma unroll
        for (int j = 0; j < NW; j++) {
            #pragma unroll
            for (int r = 0; r < 4; r++) {
                int col = w * MW * 16 + i * 16 + quad * 4 + r;
                int t   = t0 + j * 16 + l16;
                if (t < 501) {
                    float v = acc[i][j][r] + biasS[col];
                    hout[(size_t)n * 256 * 501 + (size_t)col * 501 + t] = __float2bfloat16(v);
                    lsum += v; lsq += v * v;
                }
            }
        }
    }
    red[tid] = lsum; red[256 + tid] = lsq;
    __syncthreads();
    for (int st = 128; st > 0; st >>= 1) {
        if (tid < st) { red[tid] += red[tid + st]; red[256 + tid] += red[256 + tid + st]; }
        __syncthreads();
    }
    if (tid == 0) { atomicAdd(&ssum[n], red[0]); atomicAdd(&ssq[n], red[256]); }
}

// ---------------------------------------------------------------------------
// Readout 1x1 with fused GN5+GELU
// ---------------------------------------------------------------------------
__global__ __launch_bounds__(256) void readout_gn_k(
    const bf16* __restrict__ h5, const float* __restrict__ row,
    const float* __restrict__ rob, const float* __restrict__ g5,
    const float* __restrict__ be5, const float* __restrict__ mu5,
    const float* __restrict__ rstd5, float* __restrict__ lat)
{
    __shared__ float lh[2112];   // [c][t] 64 x 33
    __shared__ float lw[4096];
    __shared__ float lb[64];
    const int n = blockIdx.x, tid = threadIdx.x;
    const float mu = mu5[n], rs = rstd5[n];
    for (int idx = tid; idx < 2112; idx += 256) {
        int c = idx / 33;
        float a = rs * g5[c];
        float v = __bfloat162float(h5[(size_t)n * 2112 + idx]) * a + (be5[c] - mu * a);
        lh[idx] = gelu_f(v);
    }
    for (int idx = tid; idx < 4096; idx += 256) lw[idx] = row[idx];
    if (tid < 64) lb[tid] = rob[tid];
    __syncthreads();
    for (int idx = tid; idx < 2112; idx += 256) {
        int t = idx >> 6, d = idx & 63;
        float a = lb[d];
        #pragma unroll 8
        for (int c = 0; c < 64; c++) a += lh[c * 33 + t] * lw[c * 64 + d];
        lat[(size_t)n * 2112 + idx] = a;   // [t][d]
    }
}

// ---------------------------------------------------------------------------
__global__ __launch_bounds__(256) void msg_pre_k(
    const float* __restrict__ lat, const float* __restrict__ W,
    const float* __restrict__ b, float* __restrict__ A, float* __restrict__ Bv)
{
    __shared__ float ll[2112];
    __shared__ float lw[8192];
    __shared__ float lb[64];
    const int n = blockIdx.x, tid = threadIdx.x;
    for (int idx = tid; idx < 2112; idx += 256) ll[idx] = lat[(size_t)n * 2112 + idx];
    for (int idx = tid; idx < 8192; idx += 256) lw[idx] = W[idx];
    if (tid < 64) lb[tid] = b[tid];
    __syncthreads();
    for (int idx = tid; idx < 2112; idx += 256) {
        int t = idx >> 6, d = idx & 63;
        float a = 0.f, bb = lb[d];
        #pragma unroll 8
        for (int k = 0; k < 64; k++) {
            float xv = ll[t * 64 + k];
            a  += xv * lw[k * 64 + d];
            bb += xv * lw[(64 + k) * 64 + d];
        }
        A[(size_t)n * 2112 + idx]  = a;
        Bv[(size_t)n * 2112 + idx] = bb;
    }
}

__global__ __launch_bounds__(256) void msg_comb_k(
    const float* __restrict__ latin, const float* __restrict__ A,
    const float* __restrict__ Bv, float* __restrict__ latout)
{
    const int n = blockIdx.x, tid = threadIdx.x;
    const int b9 = (n / 9) * 9, j = n - b9;
    for (int idx = tid; idx < 2112; idx += 256) {
        float base = Bv[(size_t)n * 2112 + idx];
        float s = 0.f;
        #pragma unroll
        for (int i = 0; i < 9; i++) {
            if (i == j) continue;
            float v = A[(size_t)(b9 + i) * 2112 + idx] + base;
            s += fmaxf(v, 0.f);
        }
        latout[(size_t)n * 2112 + idx] = latin[(size_t)n * 2112 + idx] + s * 0.125f;
    }
}

// ---------------------------------------------------------------------------
__global__ __launch_bounds__(256) void final_k(
    const float* __restrict__ lat,
    const float* __restrict__ w1, const float* __restrict__ b1,
    const float* __restrict__ w2, const float* __restrict__ b2,
    const float* __restrict__ pw, const float* __restrict__ pb,
    float* __restrict__ out)
{
    __shared__ float ly[2112], lz[2112];
    __shared__ float lw1[4096], lw2[4096], lpw[2048];
    __shared__ float lb1[64], lb2[64], lpb[32];
    const int b = blockIdx.x, tid = threadIdx.x;
    for (int idx = tid; idx < 4096; idx += 256) { lw1[idx] = w1[idx]; lw2[idx] = w2[idx]; }
    for (int idx = tid; idx < 2048; idx += 256) lpw[idx] = pw[idx];
    if (tid < 64) { lb1[tid] = b1[tid]; lb2[tid] = b2[tid]; }
    if (tid < 32) lpb[tid] = pb[tid];
    for (int idx = tid; idx < 2112; idx += 256) {
        float s = 0.f;
        #pragma unroll
        for (int jj = 0; jj < 9; jj++) s += lat[((size_t)b * 9 + jj) * 2112 + idx];
        ly[idx] = s;
    }
    __syncthreads();
    for (int idx = tid; idx < 2112; idx += 256) {
        int t = idx >> 6, d = idx & 63;
        float s = lb1[d];
        #pragma unroll 8
        for (int k = 0; k < 64; k++) s += ly[t * 64 + k] * lw1[k * 64 + d];
        lz[idx] = fmaxf(s, 0.f);
    }
    __syncthreads();
    for (int idx = tid; idx < 2112; idx += 256) {
        int t = idx >> 6, d = idx & 63;
        float s = lb2[d];
        #pragma unroll 8
        for (int k = 0; k < 64; k++) s += lz[t * 64 + k] * lw2[k * 64 + d];
        ly[idx] = s * (1.f / 9.f);
    }
    __syncthreads();
    for (int idx = tid; idx < 1056; idx += 256) {
        int e = idx / 33, t = idx - e * 33;
        float s = lpb[e];
        #pragma unroll 8
        for (int d = 0; d < 64; d++) s += ly[t * 64 + d] * lpw[d * 32 + e];
        out[(size_t)b * 1056 + idx] = s;
    }
}

// ---------------------------------------------------------------------------
extern "C" void kernel_launch(void* const* d_in, const int* in_sizes, int n_in,
                              void* d_out, int out_size, void* d_ws, size_t ws_size,
                              hipStream_t stream)
{
    const float* x = (const float*)d_in[0];
    const float* cw[6]; const float* cb[6]; const float* gg[6]; const float* gb[6];
    for (int l = 0; l < 6; l++) {
        cw[l] = (const float*)d_in[1 + 4 * l];
        cb[l] = (const float*)d_in[2 + 4 * l];
        gg[l] = (const float*)d_in[3 + 4 * l];
        gb[l] = (const float*)d_in[4 + 4 * l];
    }
    const float* ro_w = (const float*)d_in[25];
    const float* ro_b = (const float*)d_in[26];
    const float* mw0  = (const float*)d_in[27];
    const float* mb0  = (const float*)d_in[28];
    const float* mw1  = (const float*)d_in[29];
    const float* mb1  = (const float*)d_in[30];
    const float* rw1  = (const float*)d_in[31];
    const float* rb1  = (const float*)d_in[32];
    const float* rw2  = (const float*)d_in[33];
    const float* rb2  = (const float*)d_in[34];
    const float* pw   = (const float*)d_in[35];
    const float* pb   = (const float*)d_in[36];

    // ---- workspace layout (ws_size >= 256 MiB measured via harness 0xAA fill;
    //      peak here = 259.0 MB) ----
    char* ws = (char*)d_ws;
    bf16* h1 = (bf16*)(ws);                 // [576][256][501]  147,750,912 B
    bf16* h2 = (bf16*)(ws + 147750912);     // [576][256][251]   74,022,912 B
    bf16* h3 = (bf16*)(ws + 221773824);     // [576][256][126]   37,158,912 B -> end 258,932,736
    bf16* h4 = (bf16*)(ws);                 // [576][256][64]    (h1 dead)
    bf16* h5 = (bf16*)(ws + 147750912);     // [576][64][33]     (h2 dead)
    float* latA  = (float*)(ws);            // lat region overlays h4 (dead after conv5)
    float* latB  = latA  + 1216512;
    float* Aarr  = latB  + 1216512;
    float* Bvarr = Aarr  + 1216512;
    float* stat  = (float*)(ws + 258932736);
    float* mu0   = stat;          float* rstd0 = stat + 576;
    float* ssumA = stat + 1152;
    float* ssqA  = ssumA + 5 * 576;
    float* muA   = ssqA + 5 * 576;
    float* rstdA = muA + 5 * 576;
    #define SSUM(l) (ssumA + ((l) - 1) * 576)
    #define SSQ(l)  (ssqA  + ((l) - 1) * 576)
    #define MU(l)   (muA   + ((l) - 1) * 576)
    #define RSTD(l) (rstdA + ((l) - 1) * 576)

    zero_k<<<(5760 + 255) / 256, 256, 0, stream>>>(ssumA, 2 * 5 * 576);
    conv0_stats_k<<<576, 256, 0, stream>>>(x, cw[0], cb[0], mu0, rstd0);

    // ---- layer 1 (conv0 recompute fused into staging) ----
    conv1_mfma_k<<<dim3(4, 576), 256, 0, stream>>>(
        x, cw[0], cb[0], gg[0], gb[0], mu0, rstd0, cw[1], cb[1], h1, SSUM(1), SSQ(1));
    gn_stats_k<<<3, 256, 0, stream>>>(SSUM(1), SSQ(1), MU(1), RSTD(1), 1.f / (256.f * 501.f), 576);

    // ---- layer 2 ----
    convN_mfma_k<4, 8><<<dim3(2, 576), 256, 0, stream>>>(
        h1, cw[2], cb[2], gg[1], gb[1], MU(1), RSTD(1), h2, SSUM(2), SSQ(2), 501, 251);
    gn_stats_k<<<3, 256, 0, stream>>>(SSUM(2), SSQ(2), MU(2), RSTD(2), 1.f / (256.f * 251.f), 576);

    // ---- layer 3 ----
    convN_mfma_k<4, 8><<<dim3(1, 576), 256, 0, stream>>>(
        h2, cw[3], cb[3], gg[2], gb[2], MU(2), RSTD(2), h3, SSUM(3), SSQ(3), 251, 126);
    gn_stats_k<<<3, 256, 0, stream>>>(SSUM(3), SSQ(3), MU(3), RSTD(3), 1.f / (256.f * 126.f), 576);

    // ---- layer 4 ----
    convN_mfma_k<4, 4><<<dim3(1, 576), 256, 0, stream>>>(
        h3, cw[4], cb[4], gg[3], gb[3], MU(3), RSTD(3), h4, SSUM(4), SSQ(4), 126, 64);
    gn_stats_k<<<3, 256, 0, stream>>>(SSUM(4), SSQ(4), MU(4), RSTD(4), 1.f / (256.f * 64.f), 576);

    // ---- layer 5 (CO=64) ----
    convN_mfma_k<1, 4><<<dim3(1, 576), 256, 0, stream>>>(
        h4, cw[5], cb[5], gg[4], gb[4], MU(4), RSTD(4), h5, SSUM(5), SSQ(5), 64, 33);
    gn_stats_k<<<3, 256, 0, stream>>>(SSUM(5), SSQ(5), MU(5), RSTD(5), 1.f / (64.f * 33.f), 576);

    // ---- readout (fused GN5+GELU) + message passing + head ----
    readout_gn_k<<<576, 256, 0, stream>>>(h5, ro_w, ro_b, gg[5], gb[5], MU(5), RSTD(5), latA);
    msg_pre_k<<<576, 256, 0, stream>>>(latA, mw0, mb0, Aarr, Bvarr);
    msg_comb_k<<<576, 256, 0, stream>>>(latA, Aarr, Bvarr, latB);
    msg_pre_k<<<576, 256, 0, stream>>>(latB, mw1, mb1, Aarr, Bvarr);
    msg_comb_k<<<576, 256, 0, stream>>>(latB, Aarr, Bvarr, latA);
    final_k<<<64, 256, 0, stream>>>(latA, rw1, rb1, rw2, rb2, pw, pb, (float*)d_out);
}

// Round 5
// 1156.922 us; speedup vs baseline: 4.9670x; 1.2126x over previous
//
#include <hip/hip_runtime.h>
#include <hip/hip_bf16.h>

typedef __hip_bfloat16 bf16;
typedef __attribute__((ext_vector_type(8))) short s8v;   // 8 bf16 (16B)
typedef __attribute__((ext_vector_type(4))) float f4v;   // 4 f32 (C/D frag)

// Branch-free erf (A&S 7.1.26), |err| < 1.5e-7 — exact at bf16 resolution.
__device__ __forceinline__ float erf_approx(float x) {
    float ax = fabsf(x);
    float t = 1.0f / (1.0f + 0.3275911f * ax);
    float p = t * (0.254829592f + t * (-0.284496736f + t * (1.421413741f
              + t * (-1.453152027f + t * 1.061405429f))));
    float r = 1.0f - p * __expf(-ax * ax);
    return copysignf(r, x);
}
__device__ __forceinline__ float gelu_f(float v) {
    return 0.5f * v * (1.f + erf_approx(v * 0.70710678118654752440f));
}
__device__ __forceinline__ unsigned short f2bf_u(float f) {
    bf16 b = __float2bfloat16(f);
    return *(unsigned short*)&b;
}
__device__ __forceinline__ float bfu2f(unsigned short u) {
    bf16 b = *(bf16*)&u;
    return __bfloat162float(b);
}

// ---------------------------------------------------------------------------
__global__ __launch_bounds__(256) void zero_k(float* __restrict__ p, int n) {
    int i = blockIdx.x * 256 + threadIdx.x;
    if (i < n) p[i] = 0.f;
}

// ---------------------------------------------------------------------------
// Convert conv weights W1..W5 fp32 -> bf16 (concatenated), once per call.
// ---------------------------------------------------------------------------
__global__ __launch_bounds__(256) void wcvt_k(
    const float* __restrict__ w1, const float* __restrict__ w2,
    const float* __restrict__ w3, const float* __restrict__ w4,
    const float* __restrict__ w5, bf16* __restrict__ dst)
{
    int i = blockIdx.x * 256 + threadIdx.x;
    if (i >= 557056) return;
    float v;
    if      (i < 131072) v = w1[i];
    else if (i < 262144) v = w2[i - 131072];
    else if (i < 393216) v = w3[i - 262144];
    else if (i < 524288) v = w4[i - 393216];
    else                 v = w5[i - 524288];
    dst[i] = __float2bfloat16(v);
}

// ---------------------------------------------------------------------------
// conv0 channel-collapse coefficients: s = sum_co (w0,w1,w2,b);
// quadratic-form coeffs of sum_co v^2 over xt=(x0,x1,x2,1).
// coef[0..3]=s0..s3, [4..6]=A0..A2 (x_i^2), [7]=A3 (const), [8..10]=2*B01,2*B02,2*B12,
// [11..13]=2*C0,2*C1,2*C2.
// ---------------------------------------------------------------------------
__global__ __launch_bounds__(256) void m0red_k(
    const float* __restrict__ W0, const float* __restrict__ b0, float* __restrict__ coef)
{
    __shared__ float red[256];
    const int co = threadIdx.x;
    float w0 = W0[3 * co], w1 = W0[3 * co + 1], w2 = W0[3 * co + 2], b = b0[co];
    float vals[14] = {w0, w1, w2, b,
                      w0 * w0, w1 * w1, w2 * w2, b * b,
                      2.f * w0 * w1, 2.f * w0 * w2, 2.f * w1 * w2,
                      2.f * w0 * b, 2.f * w1 * b, 2.f * w2 * b};
    for (int k = 0; k < 14; k++) {
        red[co] = vals[k];
        __syncthreads();
        for (int st = 128; st > 0; st >>= 1) {
            if (co < st) red[co] += red[co + st];
            __syncthreads();
        }
        if (co == 0) coef[k] = red[0];
        __syncthreads();
    }
}

// ---------------------------------------------------------------------------
// GN0 stats per node via the collapsed quadratic form. One block per node.
// xsl[i] = x[i-4] (4-float zero pad keeps float4 reads aligned).
// ---------------------------------------------------------------------------
__global__ __launch_bounds__(256) void c0stats_k(
    const float* __restrict__ x, const float* __restrict__ coef,
    float* __restrict__ mu0, float* __restrict__ rstd0)
{
    __shared__ float xsl[3008];
    __shared__ float red[512];
    const int n = blockIdx.x, tid = threadIdx.x;
    const float* xr = x + (size_t)n * 3000;
    for (int i = tid; i < 750; i += 256) *(float4*)&xsl[4 + 4 * i] = *(const float4*)(xr + 4 * i);
    if (tid < 4) xsl[tid] = 0.f;
    float c[14];
    #pragma unroll
    for (int k = 0; k < 14; k++) c[k] = coef[k];
    __syncthreads();
    float S = 0.f, Q = 0.f;
    if (tid < 250) {
        float f[16];
        #pragma unroll
        for (int k = 0; k < 4; k++) *(float4*)&f[4 * k] = *(const float4*)&xsl[12 * tid + 4 * k];
        #pragma unroll
        for (int j = 0; j < 4; j++) {
            float x0 = f[3 * j + 3], x1 = f[3 * j + 4], x2 = f[3 * j + 5];
            S += c[0] * x0 + c[1] * x1 + c[2] * x2 + c[3];
            Q += c[4] * x0 * x0 + c[5] * x1 * x1 + c[6] * x2 * x2 + c[7]
               + c[8] * x0 * x1 + c[9] * x0 * x2 + c[10] * x1 * x2
               + c[11] * x0 + c[12] * x1 + c[13] * x2;
        }
    }
    red[tid] = S; red[256 + tid] = Q;
    __syncthreads();
    for (int st = 128; st > 0; st >>= 1) {
        if (tid < st) { red[tid] += red[tid + st]; red[256 + tid] += red[256 + tid + st]; }
        __syncthreads();
    }
    if (tid == 0) {
        float m = red[0] * (1.f / 256000.f);
        float var = red[256] * (1.f / 256000.f) - m * m;
        mu0[n] = m;
        rstd0[n] = rsqrtf(var + 1e-5f);
    }
}

// ---------------------------------------------------------------------------
// h0g = gelu(gn0(conv0(x))) as bf16, node-chunked. Block: (ci-block of 32) x n.
// Thread: ci = ci0 + tid>>3, handles t-quads q8 + 8s. Full occupancy, b128 LDS reads.
// ---------------------------------------------------------------------------
__global__ __launch_bounds__(256) void h0g_k(
    const float* __restrict__ x, const float* __restrict__ W0,
    const float* __restrict__ b0, const float* __restrict__ g0,
    const float* __restrict__ be0, const float* __restrict__ mu0,
    const float* __restrict__ rstd0, bf16* __restrict__ h0g, int n0)
{
    __shared__ float xsl[3008];
    const int z = blockIdx.y;
    const int n = n0 + z;
    const int ci = blockIdx.x * 32 + (threadIdx.x >> 3);
    const int q8 = threadIdx.x & 7;
    const int tid = threadIdx.x;
    const float* xr = x + (size_t)n * 3000;
    for (int i = tid; i < 750; i += 256) *(float4*)&xsl[4 + 4 * i] = *(const float4*)(xr + 4 * i);
    if (tid < 4) xsl[tid] = 0.f;
    const float w0 = W0[3 * ci], w1 = W0[3 * ci + 1], w2 = W0[3 * ci + 2];
    const float rs = rstd0[n], m = mu0[n];
    const float A = rs * g0[ci];
    const float C = (b0[ci] - m) * A + be0[ci];
    __syncthreads();
    bf16* orow = h0g + (size_t)z * 256000 + (size_t)ci * 1000;
    for (int s = 0; s < 32; s++) {
        int qd = q8 + 8 * s;
        if (qd >= 250) break;
        float f[16];
        #pragma unroll
        for (int k = 0; k < 4; k++) *(float4*)&f[4 * k] = *(const float4*)&xsl[12 * qd + 4 * k];
        ushort4 pk;
        unsigned short* pu = (unsigned short*)&pk;
        #pragma unroll
        for (int j = 0; j < 4; j++) {
            float conv = w0 * f[3 * j + 3] + w1 * f[3 * j + 4] + w2 * f[3 * j + 5];
            pu[j] = f2bf_u(gelu_f(conv * A + C));
        }
        *(ushort4*)&orow[4 * qd] = pk;
    }
}

// ---------------------------------------------------------------------------
// In-place GN + GELU on raw conv output (reads ssum/ssq, stats inline).
// Vectorized ushort8; c tracked incrementally (CT % 8 == 0 for all layers).
// ---------------------------------------------------------------------------
template<int C, int T>
__global__ __launch_bounds__(256) void gn_gelu_k(
    bf16* __restrict__ h, const float* __restrict__ ssum, const float* __restrict__ ssq,
    const float* __restrict__ gam, const float* __restrict__ bet, float invCT)
{
    constexpr unsigned CT = (unsigned)C * (unsigned)T;
    constexpr long total = 576L * CT;
    long I = ((long)blockIdx.x * 256 + threadIdx.x) * 8;
    if (I >= total) return;
    unsigned n = (unsigned)(I / CT);
    unsigned r = (unsigned)(I - (long)n * CT);
    unsigned c = r / T;
    unsigned rem = r - c * T;
    float m = ssum[n] * invCT;
    float rs = rsqrtf(ssq[n] * invCT - m * m + 1e-5f);
    s8v v8 = *(s8v*)&h[I];
    unsigned short* uu = (unsigned short*)&v8;
    #pragma unroll
    for (int j = 0; j < 8; j++) {
        float a = rs * gam[c];
        float v = bfu2f(uu[j]) * a + (bet[c] - m * a);
        uu[j] = f2bf_u(gelu_f(v));
        rem++;
        if (rem == (unsigned)T) { c++; rem = 0; }
    }
    *(s8v*)&h[I] = v8;
}

// ===========================================================================
// Pure-bf16 MFMA conv GEMM (stride-2/width-2/pad-1; im2col = deinterleave).
// M = CO = MW*64 (4 waves along M), N = NB = NW*16 t, K = 512, chunks of 64.
// Identity B staging (input already transformed). Raw out + GN stat atomics.
// ===========================================================================
template<int MW, int NW>
__global__ __launch_bounds__(256, 3) void convG_k(
    const bf16* __restrict__ g, const bf16* __restrict__ Wbf,
    const float* __restrict__ bias, bf16* __restrict__ hout,
    float* __restrict__ ssum, float* __restrict__ ssq,
    int T_g, int T_out, int n0)
{
    constexpr int MB = MW * 64;
    constexpr int NB = NW * 16;
    __shared__ bf16 aT[MB][72];
    __shared__ bf16 xim[NB][72];
    __shared__ float biasS[MB];
    __shared__ float red[512];
    const int n  = blockIdx.y;
    const int t0 = blockIdx.x * NB;
    const int tid = threadIdx.x;
    for (int i = tid; i < MB; i += 256) biasS[i] = bias[i];
    const int w = tid >> 6, lane = tid & 63;
    const int l16 = lane & 15, quad = lane >> 4;
    f4v acc[MW][NW];
    #pragma unroll
    for (int i = 0; i < MW; i++)
        #pragma unroll
        for (int j = 0; j < NW; j++) acc[i][j] = (f4v){0.f, 0.f, 0.f, 0.f};
    const bf16* xb = g + (size_t)n * 256 * T_g;

    for (int ci0 = 0; ci0 < 256; ci0 += 32) {
        // A: bf16 W slice, b128 global -> b128 LDS
        for (int e = tid; e < MB * 8; e += 256) {
            int mm = e >> 3, u = e & 7;
            s8v wv = *(const s8v*)(Wbf + (size_t)mm * 512 + ci0 * 2 + u * 8);
            *(s8v*)&aT[mm][u * 8] = wv;
        }
        // B: identity deinterleave, p-minor (coalesced)
        for (int e = tid; e < NB * 32; e += 256) {
            int p = e % NB, ci2 = e / NB;
            int tin = 2 * (t0 + p) - 1;
            const bf16* r = xb + (size_t)(ci0 + ci2) * T_g;
            unsigned short u0 = 0, u1 = 0;
            if (tin >= 0 && tin < T_g) u0 = *(const unsigned short*)&r[tin];
            if (tin + 1 < T_g)         u1 = *(const unsigned short*)&r[tin + 1];
            *(unsigned*)&xim[p][2 * ci2] = (unsigned)u0 | ((unsigned)u1 << 16);
        }
        __syncthreads();
        #pragma unroll
        for (int ks = 0; ks < 2; ks++) {
            s8v af[MW], bfr[NW];
            #pragma unroll
            for (int i = 0; i < MW; i++)
                af[i] = *(const s8v*)&aT[w * MW * 16 + i * 16 + l16][ks * 32 + quad * 8];
            #pragma unroll
            for (int j = 0; j < NW; j++)
                bfr[j] = *(const s8v*)&xim[j * 16 + l16][ks * 32 + quad * 8];
            #pragma unroll
            for (int i = 0; i < MW; i++)
                #pragma unroll
                for (int j = 0; j < NW; j++)
                    acc[i][j] = __builtin_amdgcn_mfma_f32_16x16x32_bf16(af[i], bfr[j], acc[i][j], 0, 0, 0);
        }
        __syncthreads();
    }
    float lsum = 0.f, lsq = 0.f;
    #pragma unroll
    for (int i = 0; i < MW; i++) {
        #pragma unroll
        for (int j = 0; j < NW; j++) {
            #pragma unroll
            for (int r = 0; r < 4; r++) {
                int col = w * MW * 16 + i * 16 + quad * 4 + r;
                int t   = t0 + j * 16 + l16;
                if (t < T_out) {
                    float v = acc[i][j][r] + biasS[col];
                    hout[(size_t)n * MB * T_out + (size_t)col * T_out + t] = __float2bfloat16(v);
                    lsum += v; lsq += v * v;
                }
            }
        }
    }
    red[tid] = lsum; red[256 + tid] = lsq;
    __syncthreads();
    for (int st = 128; st > 0; st >>= 1) {
        if (tid < st) { red[tid] += red[tid + st]; red[256 + tid] += red[256 + tid + st]; }
        __syncthreads();
    }
    if (tid == 0) { atomicAdd(&ssum[n0 + n], red[0]); atomicAdd(&ssq[n0 + n], red[256]); }
}

// ---------------------------------------------------------------------------
// Readout 1x1 with inline GN5 stats + GELU
// ---------------------------------------------------------------------------
__global__ __launch_bounds__(256) void readout_gn_k(
    const bf16* __restrict__ h5, const float* __restrict__ row,
    const float* __restrict__ rob, const float* __restrict__ g5,
    const float* __restrict__ be5, const float* __restrict__ ssum,
    const float* __restrict__ ssq, float invCT, float* __restrict__ lat)
{
    __shared__ float lh[2112];   // [c][t] 64 x 33
    __shared__ float lw[4096];
    __shared__ float lb[64];
    const int n = blockIdx.x, tid = threadIdx.x;
    const float mu = ssum[n] * invCT;
    const float rs = rsqrtf(ssq[n] * invCT - mu * mu + 1e-5f);
    for (int idx = tid; idx < 2112; idx += 256) {
        int c = idx / 33;
        float a = rs * g5[c];
        float v = __bfloat162float(h5[(size_t)n * 2112 + idx]) * a + (be5[c] - mu * a);
        lh[idx] = gelu_f(v);
    }
    for (int idx = tid; idx < 4096; idx += 256) lw[idx] = row[idx];
    if (tid < 64) lb[tid] = rob[tid];
    __syncthreads();
    for (int idx = tid; idx < 2112; idx += 256) {
        int t = idx >> 6, d = idx & 63;
        float a = lb[d];
        #pragma unroll 8
        for (int c = 0; c < 64; c++) a += lh[c * 33 + t] * lw[c * 64 + d];
        lat[(size_t)n * 2112 + idx] = a;   // [t][d]
    }
}

// ---------------------------------------------------------------------------
__global__ __launch_bounds__(256) void msg_pre_k(
    const float* __restrict__ lat, const float* __restrict__ W,
    const float* __restrict__ b, float* __restrict__ A, float* __restrict__ Bv)
{
    __shared__ float ll[2112];
    __shared__ float lw[8192];
    __shared__ float lb[64];
    const int n = blockIdx.x, tid = threadIdx.x;
    for (int idx = tid; idx < 2112; idx += 256) ll[idx] = lat[(size_t)n * 2112 + idx];
    for (int idx = tid; idx < 8192; idx += 256) lw[idx] = W[idx];
    if (tid < 64) lb[tid] = b[tid];
    __syncthreads();
    for (int idx = tid; idx < 2112; idx += 256) {
        int t = idx >> 6, d = idx & 63;
        float a = 0.f, bb = lb[d];
        #pragma unroll 8
        for (int k = 0; k < 64; k++) {
            float xv = ll[t * 64 + k];
            a  += xv * lw[k * 64 + d];
            bb += xv * lw[(64 + k) * 64 + d];
        }
        A[(size_t)n * 2112 + idx]  = a;
        Bv[(size_t)n * 2112 + idx] = bb;
    }
}

__global__ __launch_bounds__(256) void msg_comb_k(
    const float* __restrict__ latin, const float* __restrict__ A,
    const float* __restrict__ Bv, float* __restrict__ latout)
{
    const int n = blockIdx.x, tid = threadIdx.x;
    const int b9 = (n / 9) * 9, j = n - b9;
    for (int idx = tid; idx < 2112; idx += 256) {
        float base = Bv[(size_t)n * 2112 + idx];
        float s = 0.f;
        #pragma unroll
        for (int i = 0; i < 9; i++) {
            if (i == j) continue;
            float v = A[(size_t)(b9 + i) * 2112 + idx] + base;
            s += fmaxf(v, 0.f);
        }
        latout[(size_t)n * 2112 + idx] = latin[(size_t)n * 2112 + idx] + s * 0.125f;
    }
}

// ---------------------------------------------------------------------------
__global__ __launch_bounds__(256) void final_k(
    const float* __restrict__ lat,
    const float* __restrict__ w1, const float* __restrict__ b1,
    const float* __restrict__ w2, const float* __restrict__ b2,
    const float* __restrict__ pw, const float* __restrict__ pb,
    float* __restrict__ out)
{
    __shared__ float ly[2112], lz[2112];
    __shared__ float lw1[4096], lw2[4096], lpw[2048];
    __shared__ float lb1[64], lb2[64], lpb[32];
    const int b = blockIdx.x, tid = threadIdx.x;
    for (int idx = tid; idx < 4096; idx += 256) { lw1[idx] = w1[idx]; lw2[idx] = w2[idx]; }
    for (int idx = tid; idx < 2048; idx += 256) lpw[idx] = pw[idx];
    if (tid < 64) { lb1[tid] = b1[tid]; lb2[tid] = b2[tid]; }
    if (tid < 32) lpb[tid] = pb[tid];
    for (int idx = tid; idx < 2112; idx += 256) {
        float s = 0.f;
        #pragma unroll
        for (int jj = 0; jj < 9; jj++) s += lat[((size_t)b * 9 + jj) * 2112 + idx];
        ly[idx] = s;
    }
    __syncthreads();
    for (int idx = tid; idx < 2112; idx += 256) {
        int t = idx >> 6, d = idx & 63;
        float s = lb1[d];
        #pragma unroll 8
        for (int k = 0; k < 64; k++) s += ly[t * 64 + k] * lw1[k * 64 + d];
        lz[idx] = fmaxf(s, 0.f);
    }
    __syncthreads();
    for (int idx = tid; idx < 2112; idx += 256) {
        int t = idx >> 6, d = idx & 63;
        float s = lb2[d];
        #pragma unroll 8
        for (int k = 0; k < 64; k++) s += lz[t * 64 + k] * lw2[k * 64 + d];
        ly[idx] = s * (1.f / 9.f);
    }
    __syncthreads();
    for (int idx = tid; idx < 1056; idx += 256) {
        int e = idx / 33, t = idx - e * 33;
        float s = lpb[e];
        #pragma unroll 8
        for (int d = 0; d < 64; d++) s += ly[t * 64 + d] * lpw[d * 32 + e];
        out[(size_t)b * 1056 + idx] = s;
    }
}

// ---------------------------------------------------------------------------
extern "C" void kernel_launch(void* const* d_in, const int* in_sizes, int n_in,
                              void* d_out, int out_size, void* d_ws, size_t ws_size,
                              hipStream_t stream)
{
    const float* x = (const float*)d_in[0];
    const float* cw[6]; const float* cb[6]; const float* gg[6]; const float* gb[6];
    for (int l = 0; l < 6; l++) {
        cw[l] = (const float*)d_in[1 + 4 * l];
        cb[l] = (const float*)d_in[2 + 4 * l];
        gg[l] = (const float*)d_in[3 + 4 * l];
        gb[l] = (const float*)d_in[4 + 4 * l];
    }
    const float* ro_w = (const float*)d_in[25];
    const float* ro_b = (const float*)d_in[26];
    const float* mw0  = (const float*)d_in[27];
    const float* mb0  = (const float*)d_in[28];
    const float* mw1  = (const float*)d_in[29];
    const float* mb1  = (const float*)d_in[30];
    const float* rw1  = (const float*)d_in[31];
    const float* rb1  = (const float*)d_in[32];
    const float* rw2  = (const float*)d_in[33];
    const float* rb2  = (const float*)d_in[34];
    const float* pw   = (const float*)d_in[35];
    const float* pb   = (const float*)d_in[36];

    // ---- workspace (ws_size = 268,435,456 B measured; peak used ~260.1 MB) ----
    char* ws = (char*)d_ws;
    bf16* h1  = (bf16*)(ws);                 // [576][256][501] 147,750,912 B
    bf16* h0g = (bf16*)(ws + 147750912);     // [192][256][1000] 98,304,000 B (chunk)
    bf16* h2  = (bf16*)(ws + 147750912);     // [576][256][251] 74,022,912 B (h0g dead)
    bf16* h3  = (bf16*)(ws + 221773824);     // [576][256][126] 37,158,912 B -> 258,932,736
    bf16* h4  = (bf16*)(ws);                 // [576][256][64] (h1 dead)
    bf16* h5  = (bf16*)(ws + 147750912);     // [576][64][33] (h2 dead)
    float* latA  = (float*)(ws);             // (h4 dead after conv5)
    float* latB  = latA  + 1216512;
    float* Aarr  = latB  + 1216512;
    float* Bvarr = Aarr  + 1216512;
    float* stat  = (float*)(ws + 258932736);
    float* mu0   = stat;
    float* rstd0 = stat + 576;
    float* coef  = stat + 1152;              // 16
    float* ssumA = stat + 1168;              // 5 x 576
    float* ssqA  = ssumA + 5 * 576;
    bf16*  Wbf   = (bf16*)(ws + 258965504);  // 557,056 bf16 = 1,114,112 B -> 260,079,616
    #define SSUM(l) (ssumA + ((l) - 1) * 576)
    #define SSQ(l)  (ssqA  + ((l) - 1) * 576)

    zero_k<<<(5760 + 255) / 256, 256, 0, stream>>>(ssumA, 2 * 5 * 576);
    wcvt_k<<<(557056 + 255) / 256, 256, 0, stream>>>(cw[1], cw[2], cw[3], cw[4], cw[5], Wbf);
    m0red_k<<<1, 256, 0, stream>>>(cw[0], cb[0], coef);
    c0stats_k<<<576, 256, 0, stream>>>(x, coef, mu0, rstd0);

    // ---- layer 1: h0g (chunked x3) + pure GEMM ----
    for (int c = 0; c < 3; c++) {
        int n0 = c * 192;
        h0g_k<<<dim3(8, 192), 256, 0, stream>>>(x, cw[0], cb[0], gg[0], gb[0], mu0, rstd0, h0g, n0);
        convG_k<4, 4><<<dim3(8, 192), 256, 0, stream>>>(
            h0g, Wbf, cb[1], h1 + (size_t)n0 * 256 * 501, SSUM(1), SSQ(1), 1000, 501, n0);
    }
    gn_gelu_k<256, 501><<<(9234432 + 255) / 256, 256, 0, stream>>>(
        h1, SSUM(1), SSQ(1), gg[1], gb[1], 1.f / (256.f * 501.f));

    // ---- layer 2 ----
    convG_k<4, 4><<<dim3(4, 576), 256, 0, stream>>>(
        h1, Wbf + 131072, cb[2], h2, SSUM(2), SSQ(2), 501, 251, 0);
    gn_gelu_k<256, 251><<<(4626432 + 255) / 256, 256, 0, stream>>>(
        h2, SSUM(2), SSQ(2), gg[2], gb[2], 1.f / (256.f * 251.f));

    // ---- layer 3 ----
    convG_k<4, 4><<<dim3(2, 576), 256, 0, stream>>>(
        h2, Wbf + 262144, cb[3], h3, SSUM(3), SSQ(3), 251, 126, 0);
    gn_gelu_k<256, 126><<<(2322432 + 255) / 256, 256, 0, stream>>>(
        h3, SSUM(3), SSQ(3), gg[3], gb[3], 1.f / (256.f * 126.f));

    // ---- layer 4 ----
    convG_k<4, 4><<<dim3(1, 576), 256, 0, stream>>>(
        h3, Wbf + 393216, cb[4], h4, SSUM(4), SSQ(4), 126, 64, 0);
    gn_gelu_k<256, 64><<<(1179648 + 255) / 256, 256, 0, stream>>>(
        h4, SSUM(4), SSQ(4), gg[4], gb[4], 1.f / (256.f * 64.f));

    // ---- layer 5 (CO=64) ----
    convG_k<1, 3><<<dim3(1, 576), 256, 0, stream>>>(
        h4, Wbf + 524288, cb[5], h5, SSUM(5), SSQ(5), 64, 33, 0);

    // ---- readout (inline GN5+GELU) + message passing + head ----
    readout_gn_k<<<576, 256, 0, stream>>>(h5, ro_w, ro_b, gg[5], gb[5],
                                          SSUM(5), SSQ(5), 1.f / (64.f * 33.f), latA);
    msg_pre_k<<<576, 256, 0, stream>>>(latA, mw0, mb0, Aarr, Bvarr);
    msg_comb_k<<<576, 256, 0, stream>>>(latA, Aarr, Bvarr, latB);
    msg_pre_k<<<576, 256, 0, stream>>>(latB, mw1, mb1, Aarr, Bvarr);
    msg_comb_k<<<576, 256, 0, stream>>>(latB, Aarr, Bvarr, latA);
    final_k<<<64, 256, 0, stream>>>(latA, rw1, rb1, rw2, rb2, pw, pb, (float*)d_out);
}